// Round 2
// baseline (4151.411 us; speedup 1.0000x reference)
//
#include <hip/hip_runtime.h>
#include <hip/hip_bf16.h>

typedef unsigned short u16;
typedef unsigned int u32;

#define L_SEQ 2048
#define DMODEL 2048
#define DINNER 4096
#define NSTATE 16
#define MROWS 4096   // B*L

typedef __bf16 bf16x8 __attribute__((ext_vector_type(8)));
typedef float f32x4 __attribute__((ext_vector_type(4)));

__device__ __forceinline__ u16 f2bf(float f) {
    union { float f; u32 u; } v; v.f = f;
    u32 u = v.u;
    u32 r = (u + 0x7fffu + ((u >> 16) & 1u)) >> 16;
    return (u16)r;
}
__device__ __forceinline__ float bf2f(u16 h) {
    union { u32 u; float f; } v; v.u = ((u32)h) << 16;
    return v.f;
}

__device__ __forceinline__ void gload16(const void* g, void* l) {
    __builtin_amdgcn_global_load_lds((const __attribute__((address_space(1))) void*)g,
                                     (__attribute__((address_space(3))) void*)l, 16, 0, 0);
}

// ---------------- f32 -> bf16 conversion (zero-pads tail beyond nsrc) ----------------
__global__ __launch_bounds__(256) void cvt_kernel(const float* __restrict__ src,
                                                  u16* __restrict__ dst, long nsrc) {
    long i = ((long)blockIdx.x * 256 + threadIdx.x) * 8;
    union { uint4 v; u16 u[8]; } o;
    if (i < nsrc) {
        f32x4 a = *(const f32x4*)(src + i);
        f32x4 b = *(const f32x4*)(src + i + 4);
#pragma unroll
        for (int j = 0; j < 4; ++j) { o.u[j] = f2bf(a[j]); o.u[4 + j] = f2bf(b[j]); }
    } else {
#pragma unroll
        for (int j = 0; j < 8; ++j) o.u[j] = 0;
    }
    *(uint4*)(dst + i) = o.v;
}

// ---------------- LayerNorm (D=2048) -> bf16 ----------------
__global__ __launch_bounds__(256) void ln_kernel(const float* __restrict__ in,
                                                 const float* __restrict__ w,
                                                 const float* __restrict__ b,
                                                 u16* __restrict__ out) {
    const long row = blockIdx.x;
    const float* x = in + row * DMODEL;
    const int t = threadIdx.x;
    f32x4 v0 = *(const f32x4*)(x + t * 8);
    f32x4 v1 = *(const f32x4*)(x + t * 8 + 4);
    float s = 0.f, sq = 0.f;
#pragma unroll
    for (int j = 0; j < 4; ++j) {
        s += v0[j] + v1[j];
        sq += v0[j] * v0[j] + v1[j] * v1[j];
    }
#pragma unroll
    for (int off = 32; off > 0; off >>= 1) {
        s += __shfl_down(s, off);
        sq += __shfl_down(sq, off);
    }
    __shared__ float red[8];
    __shared__ float stats[2];
    const int wid = t >> 6, lane = t & 63;
    if (lane == 0) { red[wid] = s; red[4 + wid] = sq; }
    __syncthreads();
    if (t == 0) {
        float S = red[0] + red[1] + red[2] + red[3];
        float Q = red[4] + red[5] + red[6] + red[7];
        float mu = S / (float)DMODEL;
        stats[0] = mu;
        stats[1] = rsqrtf(Q / (float)DMODEL - mu * mu + 1e-5f);
    }
    __syncthreads();
    float mu = stats[0], rstd = stats[1];
    union { uint4 v; u16 u[8]; } o;
#pragma unroll
    for (int j = 0; j < 8; ++j) {
        float xv = (j < 4) ? v0[j] : v1[j - 4];
        o.u[j] = f2bf((xv - mu) * rstd * w[t * 8 + j] + b[t * 8 + j]);
    }
    *(uint4*)(out + row * DMODEL + t * 8) = o.v;
}

// ---------------- bf16 GEMM: C[M,N] = A[M,K(lda)] @ W[N,K]^T ----------------
// MODE 0: f32 out; MODE 1: bf16 out; MODE 2: f32 out + addv
template <int MODE>
__global__ __launch_bounds__(256) void gemm_bt(const u16* __restrict__ A,
                                               const u16* __restrict__ W,
                                               float* __restrict__ Cf,
                                               u16* __restrict__ Cb,
                                               const float* __restrict__ addv,
                                               int M, int N, int K, int lda) {
    __shared__ u16 As[128 * 64];
    __shared__ u16 Bs[128 * 64];
    const int tid = threadIdx.x;
    const int wid = tid >> 6;
    const int lane = tid & 63;
    const int m0 = blockIdx.y << 7;
    const int n0 = blockIdx.x << 7;
    const int wr = (wid >> 1) << 6;
    const int wc = (wid & 1) << 6;
    const int l15 = lane & 15;
    const int lhi = lane >> 4;

    f32x4 acc[4][4];
#pragma unroll
    for (int i = 0; i < 4; ++i)
#pragma unroll
        for (int j = 0; j < 4; ++j) acc[i][j] = (f32x4){0.f, 0.f, 0.f, 0.f};

    const int srow = (wid << 3) + (lane >> 3);   // wave staging row within 32-row slab
    const int scol = (lane & 7) << 3;            // ushort column offset

    const u16* aBase = A + (long)(m0 + srow) * lda + scol;
    const u16* bBase = W + (long)(n0 + srow) * (long)K + scol;

    for (int k0 = 0; k0 < K; k0 += 64) {
#pragma unroll
        for (int i = 0; i < 4; ++i) {
            gload16(aBase + (long)(i * 32) * lda + k0, &As[((i << 5) + (wid << 3)) << 6]);
            gload16(bBase + (long)(i * 32) * K + k0, &Bs[((i << 5) + (wid << 3)) << 6]);
        }
        __syncthreads();
#pragma unroll
        for (int kk = 0; kk < 64; kk += 32) {
            bf16x8 af[4], bfr[4];
#pragma unroll
            for (int i = 0; i < 4; ++i)
                af[i] = *(const bf16x8*)&As[((wr + (i << 4) + l15) << 6) + kk + (lhi << 3)];
#pragma unroll
            for (int j = 0; j < 4; ++j)
                bfr[j] = *(const bf16x8*)&Bs[((wc + (j << 4) + l15) << 6) + kk + (lhi << 3)];
#pragma unroll
            for (int i = 0; i < 4; ++i)
#pragma unroll
                for (int j = 0; j < 4; ++j)
                    acc[i][j] = __builtin_amdgcn_mfma_f32_16x16x32_bf16(af[i], bfr[j], acc[i][j], 0, 0, 0);
        }
        __syncthreads();
    }

#pragma unroll
    for (int i = 0; i < 4; ++i) {
#pragma unroll
        for (int j = 0; j < 4; ++j) {
#pragma unroll
            for (int r = 0; r < 4; ++r) {
                int row = m0 + wr + (i << 4) + (lhi << 2) + r;
                int col = n0 + wc + (j << 4) + l15;
                long idx = (long)row * N + col;
                float v = acc[i][j][r];
                if (MODE == 2) v += addv[idx];
                if (MODE == 1) Cb[idx] = f2bf(v);
                else Cf[idx] = v;
            }
        }
    }
}

// ---------------- causal depthwise conv (K=4) + SiLU ----------------
__global__ __launch_bounds__(256) void conv_silu_kernel(const u16* __restrict__ xz,
                                                        const float* __restrict__ cw,
                                                        const float* __restrict__ cb,
                                                        float* __restrict__ xs_out,
                                                        u16* __restrict__ act_out) {
    const int d0 = (blockIdx.x * 256 + threadIdx.x) * 8;  // grid.x = DINNER/2048 = 2
    const int bl = blockIdx.y;                            // 0..MROWS-1
    const int l = bl & (L_SEQ - 1);
    float acc[8];
    float wt[8][4];
#pragma unroll
    for (int j = 0; j < 8; ++j) {
        f32x4 wj = *(const f32x4*)(cw + (d0 + j) * 4);
        wt[j][0] = wj[0]; wt[j][1] = wj[1]; wt[j][2] = wj[2]; wt[j][3] = wj[3];
        acc[j] = cb[d0 + j];
    }
#pragma unroll
    for (int k = 0; k < 4; ++k) {
        int ls = l + k - 3;
        if (ls >= 0) {
            union { uint4 v; u16 u[8]; } xv;
            xv.v = *(const uint4*)(xz + (long)(bl + k - 3) * (2 * DINNER) + d0);
#pragma unroll
            for (int j = 0; j < 8; ++j) acc[j] = fmaf(bf2f(xv.u[j]), wt[j][k], acc[j]);
        }
    }
    union { uint4 v; u16 u[8]; } ob;
    f32x4 o0, o1;
#pragma unroll
    for (int j = 0; j < 8; ++j) {
        float c = acc[j];
        float sv = c / (1.f + __expf(-c));
        if (j < 4) o0[j] = sv; else o1[j - 4] = sv;
        ob.u[j] = f2bf(sv);
    }
    long orow = (long)bl * DINNER + d0;
    *(f32x4*)(xs_out + orow) = o0;
    *(f32x4*)(xs_out + orow + 4) = o1;
    *(uint4*)(act_out + orow) = ob.v;
}

// ---------------- SSM scan over L; fuses softplus, Dp*xs, gate-SiLU ----------------
__global__ __launch_bounds__(256) void scan_kernel(const float* __restrict__ dpre,
                                                   const float* __restrict__ xs,
                                                   const u16* __restrict__ ssmb,
                                                   const u16* __restrict__ xz,
                                                   const float* __restrict__ Am,
                                                   const float* __restrict__ bdt,
                                                   const float* __restrict__ Dp,
                                                   u16* __restrict__ yb) {
    const int d = blockIdx.x * 256 + threadIdx.x;  // 0..DINNER-1
    const int b = blockIdx.y;
    float a[NSTATE];
#pragma unroll
    for (int n = 0; n < NSTATE; ++n) a[n] = Am[d * NSTATE + n] * 1.44269504088896f;
    float h[NSTATE];
#pragma unroll
    for (int n = 0; n < NSTATE; ++n) h[n] = 0.f;
    const float bd = bdt[d];
    const float dp = Dp[d];
    const long base = (long)b * L_SEQ;
    for (int l = 0; l < L_SEQ; ++l) {
        const long row = base + l;
        float dpv = dpre[row * DINNER + d] + bd;
        float delta = (dpv > 20.f) ? dpv : log1pf(__expf(dpv));
        float xt = xs[row * DINNER + d];
        float dx = delta * xt;
        const u16* sb = ssmb + row * 256;
        float y = 0.f;
#pragma unroll
        for (int n = 0; n < NSTATE; ++n) {
            float Bn = bf2f(sb[128 + n]);
            float Cn = bf2f(sb[144 + n]);
            h[n] = __builtin_amdgcn_exp2f(delta * a[n]) * h[n] + dx * Bn;
            y = fmaf(h[n], Cn, y);
        }
        float g = bf2f(xz[row * (2 * DINNER) + DINNER + d]);
        float yv = (y + dp * xt) * (g / (1.f + __expf(-g)));
        yb[row * DINNER + d] = f2bf(yv);
    }
}

// ---------------- gated MLP activation: act = yy * silu(g) ----------------
__global__ __launch_bounds__(256) void gated_act_kernel(const u16* __restrict__ gy,
                                                        u16* __restrict__ actb) {
    long i = ((long)blockIdx.x * 256 + threadIdx.x) * 8;  // over MROWS*8192
    long m = i >> 13;
    long f = i & 8191;
    const u16* gp = gy + m * 16384 + f;
    union { uint4 v; u16 u[8]; } gu, yu, ob;
    gu.v = *(const uint4*)gp;
    yu.v = *(const uint4*)(gp + 8192);
#pragma unroll
    for (int j = 0; j < 8; ++j) {
        float g = bf2f(gu.u[j]);
        float yv = bf2f(yu.u[j]);
        ob.u[j] = f2bf(yv * (g / (1.f + __expf(-g))));
    }
    *(uint4*)(actb + i) = ob.v;
}

extern "C" void kernel_launch(void* const* d_in, const int* in_sizes, int n_in,
                              void* d_out, int out_size, void* d_ws, size_t ws_size,
                              hipStream_t stream) {
    const float* hidden = (const float*)d_in[0];
    const float* ln1w   = (const float*)d_in[1];
    const float* ln1b   = (const float*)d_in[2];
    const float* W_in   = (const float*)d_in[3];
    const float* conv_w = (const float*)d_in[4];
    const float* conv_b = (const float*)d_in[5];
    const float* W_x    = (const float*)d_in[6];
    const float* W_dt   = (const float*)d_in[7];
    const float* b_dt   = (const float*)d_in[8];
    const float* Amat   = (const float*)d_in[9];
    const float* Dp     = (const float*)d_in[10];
    const float* W_out  = (const float*)d_in[11];
    const float* ln2w   = (const float*)d_in[12];
    const float* ln2b   = (const float*)d_in[13];
    const float* W_fc1  = (const float*)d_in[14];
    const float* W_fc2  = (const float*)d_in[15];
    float* out = (float*)d_out;

    char* ws = (char*)d_ws;
    const size_t SZ67 = 67108864;  // 64 MiB
    u16*   ACT   = (u16*)(ws);                       // 64MB: bf16 activations (reused)
    u16*   WB    = (u16*)(ws + SZ67);                // 64MB: bf16 weights (reused)
    u16*   XZ    = (u16*)(ws + 2 * SZ67);            // 64MB: xz bf16 (4096 x 8192)
    float* XS    = (float*)(ws + 3 * SZ67);          // 64MB: silu(conv) f32 (4096 x 4096)
    float* DELTA = (float*)(ws + 4 * SZ67);          // 64MB: delta_pre f32
    u16*   SSMB  = (u16*)(ws + 5 * SZ67);            // 2MB : ssm bf16 (4096 x 256)
    float* HS    = (float*)(ws + 5 * SZ67 + 2097152);// 32MB: residual2 f32
    u16*   GY    = XZ;                               // 128MB: spans XZ+XS (4096 x 16384)

    // 1) LN1 -> ACT (bf16)
    ln_kernel<<<MROWS, 256, 0, stream>>>(hidden, ln1w, ln1b, ACT);
    // 2) W_in -> WB
    cvt_kernel<<<(int)((8192L * 2048) / 2048), 256, 0, stream>>>(W_in, WB, 8192L * 2048);
    // 3) GEMM1: XZ = ACT @ W_in^T   (M=4096, N=8192, K=2048)
    gemm_bt<1><<<dim3(8192 / 128, MROWS / 128), 256, 0, stream>>>(ACT, WB, nullptr, XZ, nullptr,
                                                                  MROWS, 8192, 2048, 2048);
    // 4) conv + silu -> XS (f32), ACT (bf16)
    conv_silu_kernel<<<dim3(2, MROWS), 256, 0, stream>>>(XZ, conv_w, conv_b, XS, ACT);
    // 5) W_x (160x4096) -> WB zero-padded to 256 rows
    cvt_kernel<<<(int)((256L * 4096) / 2048), 256, 0, stream>>>(W_x, WB, 160L * 4096);
    // 6) GEMM2: SSMB = ACT @ W_x^T  (M=4096, N=256, K=4096), bf16 out
    gemm_bt<1><<<dim3(2, MROWS / 128), 256, 0, stream>>>(ACT, WB, nullptr, SSMB, nullptr,
                                                         MROWS, 256, 4096, 4096);
    // 7) W_dt -> WB
    cvt_kernel<<<(int)((4096L * 128) / 2048), 256, 0, stream>>>(W_dt, WB, 4096L * 128);
    // 8) GEMM3: DELTA = SSMB[:, :128] @ W_dt^T (M=4096, N=4096, K=128, lda=256), f32 out
    gemm_bt<0><<<dim3(4096 / 128, MROWS / 128), 256, 0, stream>>>(SSMB, WB, DELTA, nullptr, nullptr,
                                                                  MROWS, 4096, 128, 256);
    // 9) scan -> ACT (y bf16)
    scan_kernel<<<dim3(DINNER / 256, 2), 256, 0, stream>>>(DELTA, XS, SSMB, XZ, Amat, b_dt, Dp, ACT);
    // 10) W_out -> WB
    cvt_kernel<<<(int)((2048L * 4096) / 2048), 256, 0, stream>>>(W_out, WB, 2048L * 4096);
    // 11) GEMM4: HS = ACT @ W_out^T + hidden (M=4096, N=2048, K=4096)
    gemm_bt<2><<<dim3(2048 / 128, MROWS / 128), 256, 0, stream>>>(ACT, WB, HS, nullptr, hidden,
                                                                  MROWS, 2048, 4096, 4096);
    // 12) LN2 -> ACT
    ln_kernel<<<MROWS, 256, 0, stream>>>(HS, ln2w, ln2b, ACT);
    // 13) W_fc1 -> WB
    cvt_kernel<<<(int)((16384L * 2048) / 2048), 256, 0, stream>>>(W_fc1, WB, 16384L * 2048);
    // 14) GEMM5: GY = ACT @ W_fc1^T (M=4096, N=16384, K=2048), bf16 out
    gemm_bt<1><<<dim3(16384 / 128, MROWS / 128), 256, 0, stream>>>(ACT, WB, nullptr, GY, nullptr,
                                                                   MROWS, 16384, 2048, 2048);
    // 15) gated activation -> ACT
    gated_act_kernel<<<(int)((4096L * 8192) / 2048), 256, 0, stream>>>(GY, ACT);
    // 16) W_fc2 -> WB
    cvt_kernel<<<(int)((2048L * 8192) / 2048), 256, 0, stream>>>(W_fc2, WB, 2048L * 8192);
    // 17) GEMM6: out = ACT @ W_fc2^T + HS (M=4096, N=2048, K=8192, lda=8192)
    gemm_bt<2><<<dim3(2048 / 128, MROWS / 128), 256, 0, stream>>>(ACT, WB, out, nullptr, HS,
                                                                  MROWS, 2048, 8192, 8192);
}

// Round 3
// 1373.188 us; speedup vs baseline: 3.0232x; 3.0232x over previous
//
#include <hip/hip_runtime.h>
#include <hip/hip_bf16.h>

typedef unsigned short u16;
typedef unsigned int u32;

#define L_SEQ 2048
#define DMODEL 2048
#define DINNER 4096
#define NSTATE 16
#define MROWS 4096   // B*L
#define CHUNK 32
#define NCHK  64     // L_SEQ / CHUNK

typedef __bf16 bf16x8 __attribute__((ext_vector_type(8)));
typedef float f32x4 __attribute__((ext_vector_type(4)));

__device__ __forceinline__ u16 f2bf(float f) {
    union { float f; u32 u; } v; v.f = f;
    u32 u = v.u;
    u32 r = (u + 0x7fffu + ((u >> 16) & 1u)) >> 16;
    return (u16)r;
}
__device__ __forceinline__ float bf2f(u16 h) {
    union { u32 u; float f; } v; v.u = ((u32)h) << 16;
    return v.f;
}

__device__ __forceinline__ void gload16(const void* g, void* l) {
    __builtin_amdgcn_global_load_lds((const __attribute__((address_space(1))) void*)g,
                                     (__attribute__((address_space(3))) void*)l, 16, 0, 0);
}

// ---------------- f32 -> bf16 conversion (zero-pads tail beyond nsrc) ----------------
__global__ __launch_bounds__(256) void cvt_kernel(const float* __restrict__ src,
                                                  u16* __restrict__ dst, long nsrc) {
    long i = ((long)blockIdx.x * 256 + threadIdx.x) * 8;
    union { uint4 v; u16 u[8]; } o;
    if (i < nsrc) {
        f32x4 a = *(const f32x4*)(src + i);
        f32x4 b = *(const f32x4*)(src + i + 4);
#pragma unroll
        for (int j = 0; j < 4; ++j) { o.u[j] = f2bf(a[j]); o.u[4 + j] = f2bf(b[j]); }
    } else {
#pragma unroll
        for (int j = 0; j < 8; ++j) o.u[j] = 0;
    }
    *(uint4*)(dst + i) = o.v;
}

// ---------------- LayerNorm (D=2048) -> bf16 ----------------
__global__ __launch_bounds__(256) void ln_kernel(const float* __restrict__ in,
                                                 const float* __restrict__ w,
                                                 const float* __restrict__ b,
                                                 u16* __restrict__ out) {
    const long row = blockIdx.x;
    const float* x = in + row * DMODEL;
    const int t = threadIdx.x;
    f32x4 v0 = *(const f32x4*)(x + t * 8);
    f32x4 v1 = *(const f32x4*)(x + t * 8 + 4);
    float s = 0.f, sq = 0.f;
#pragma unroll
    for (int j = 0; j < 4; ++j) {
        s += v0[j] + v1[j];
        sq += v0[j] * v0[j] + v1[j] * v1[j];
    }
#pragma unroll
    for (int off = 32; off > 0; off >>= 1) {
        s += __shfl_down(s, off);
        sq += __shfl_down(sq, off);
    }
    __shared__ float red[8];
    __shared__ float stats[2];
    const int wid = t >> 6, lane = t & 63;
    if (lane == 0) { red[wid] = s; red[4 + wid] = sq; }
    __syncthreads();
    if (t == 0) {
        float S = red[0] + red[1] + red[2] + red[3];
        float Q = red[4] + red[5] + red[6] + red[7];
        float mu = S / (float)DMODEL;
        stats[0] = mu;
        stats[1] = rsqrtf(Q / (float)DMODEL - mu * mu + 1e-5f);
    }
    __syncthreads();
    float mu = stats[0], rstd = stats[1];
    union { uint4 v; u16 u[8]; } o;
#pragma unroll
    for (int j = 0; j < 8; ++j) {
        float xv = (j < 4) ? v0[j] : v1[j - 4];
        o.u[j] = f2bf((xv - mu) * rstd * w[t * 8 + j] + b[t * 8 + j]);
    }
    *(uint4*)(out + row * DMODEL + t * 8) = o.v;
}

// ---------------- bf16 GEMM: C[M,N] = A[M,K(lda)] @ W[N,K]^T ----------------
// MODE 0: f32 out; MODE 1: bf16 out; MODE 2: f32 out + addv
template <int MODE>
__global__ __launch_bounds__(256) void gemm_bt(const u16* __restrict__ A,
                                               const u16* __restrict__ W,
                                               float* __restrict__ Cf,
                                               u16* __restrict__ Cb,
                                               const float* __restrict__ addv,
                                               int M, int N, int K, int lda) {
    __shared__ u16 As[128 * 64];
    __shared__ u16 Bs[128 * 64];
    const int tid = threadIdx.x;
    const int wid = tid >> 6;
    const int lane = tid & 63;
    const int m0 = blockIdx.y << 7;
    const int n0 = blockIdx.x << 7;
    const int wr = (wid >> 1) << 6;
    const int wc = (wid & 1) << 6;
    const int l15 = lane & 15;
    const int lhi = lane >> 4;

    f32x4 acc[4][4];
#pragma unroll
    for (int i = 0; i < 4; ++i)
#pragma unroll
        for (int j = 0; j < 4; ++j) acc[i][j] = (f32x4){0.f, 0.f, 0.f, 0.f};

    const int srow = (wid << 3) + (lane >> 3);   // wave staging row within 32-row slab
    const int scol = (lane & 7) << 3;            // ushort column offset

    const u16* aBase = A + (long)(m0 + srow) * lda + scol;
    const u16* bBase = W + (long)(n0 + srow) * (long)K + scol;

    for (int k0 = 0; k0 < K; k0 += 64) {
#pragma unroll
        for (int i = 0; i < 4; ++i) {
            gload16(aBase + (long)(i * 32) * lda + k0, &As[((i << 5) + (wid << 3)) << 6]);
            gload16(bBase + (long)(i * 32) * K + k0, &Bs[((i << 5) + (wid << 3)) << 6]);
        }
        __syncthreads();
#pragma unroll
        for (int kk = 0; kk < 64; kk += 32) {
            bf16x8 af[4], bfr[4];
#pragma unroll
            for (int i = 0; i < 4; ++i)
                af[i] = *(const bf16x8*)&As[((wr + (i << 4) + l15) << 6) + kk + (lhi << 3)];
#pragma unroll
            for (int j = 0; j < 4; ++j)
                bfr[j] = *(const bf16x8*)&Bs[((wc + (j << 4) + l15) << 6) + kk + (lhi << 3)];
#pragma unroll
            for (int i = 0; i < 4; ++i)
#pragma unroll
                for (int j = 0; j < 4; ++j)
                    acc[i][j] = __builtin_amdgcn_mfma_f32_16x16x32_bf16(af[i], bfr[j], acc[i][j], 0, 0, 0);
        }
        __syncthreads();
    }

#pragma unroll
    for (int i = 0; i < 4; ++i) {
#pragma unroll
        for (int j = 0; j < 4; ++j) {
#pragma unroll
            for (int r = 0; r < 4; ++r) {
                int row = m0 + wr + (i << 4) + (lhi << 2) + r;
                int col = n0 + wc + (j << 4) + l15;
                long idx = (long)row * N + col;
                float v = acc[i][j][r];
                if (MODE == 2) v += addv[idx];
                if (MODE == 1) Cb[idx] = f2bf(v);
                else Cf[idx] = v;
            }
        }
    }
}

// ---------------- causal depthwise conv (K=4) + SiLU ----------------
__global__ __launch_bounds__(256) void conv_silu_kernel(const u16* __restrict__ xz,
                                                        const float* __restrict__ cw,
                                                        const float* __restrict__ cb,
                                                        float* __restrict__ xs_out,
                                                        u16* __restrict__ act_out) {
    const int d0 = (blockIdx.x * 256 + threadIdx.x) * 8;  // grid.x = DINNER/2048 = 2
    const int bl = blockIdx.y;                            // 0..MROWS-1
    const int l = bl & (L_SEQ - 1);
    float acc[8];
    float wt[8][4];
#pragma unroll
    for (int j = 0; j < 8; ++j) {
        f32x4 wj = *(const f32x4*)(cw + (d0 + j) * 4);
        wt[j][0] = wj[0]; wt[j][1] = wj[1]; wt[j][2] = wj[2]; wt[j][3] = wj[3];
        acc[j] = cb[d0 + j];
    }
#pragma unroll
    for (int k = 0; k < 4; ++k) {
        int ls = l + k - 3;
        if (ls >= 0) {
            union { uint4 v; u16 u[8]; } xv;
            xv.v = *(const uint4*)(xz + (long)(bl + k - 3) * (2 * DINNER) + d0);
#pragma unroll
            for (int j = 0; j < 8; ++j) acc[j] = fmaf(bf2f(xv.u[j]), wt[j][k], acc[j]);
        }
    }
    union { uint4 v; u16 u[8]; } ob;
    f32x4 o0, o1;
#pragma unroll
    for (int j = 0; j < 8; ++j) {
        float c = acc[j];
        float sv = c / (1.f + __expf(-c));
        if (j < 4) o0[j] = sv; else o1[j - 4] = sv;
        ob.u[j] = f2bf(sv);
    }
    long orow = (long)bl * DINNER + d0;
    *(f32x4*)(xs_out + orow) = o0;
    *(f32x4*)(xs_out + orow + 4) = o1;
    *(uint4*)(act_out + orow) = ob.v;
}

// ---------------- SSM chunked scan pass 1: local scan from h=0 ----------------
// dpre is overwritten with softplus(dpre + b_dt) (= delta) for pass 3 reuse.
__global__ __launch_bounds__(256) void scan1_kernel(float* __restrict__ dpre,
                                                    const float* __restrict__ xs,
                                                    const u16* __restrict__ ssmb,
                                                    const float* __restrict__ Am,
                                                    const float* __restrict__ bdt,
                                                    float* __restrict__ hend,   // [B][NCHK][DINNER][NSTATE]
                                                    float* __restrict__ sumd) { // [B][NCHK][DINNER]
    const int d = blockIdx.x * 256 + threadIdx.x;
    const int c = blockIdx.y;
    const int b = blockIdx.z;
    float a2[NSTATE];
#pragma unroll
    for (int n = 0; n < NSTATE; ++n) a2[n] = Am[d * NSTATE + n] * 1.4426950408889634f;
    float h[NSTATE];
#pragma unroll
    for (int n = 0; n < NSTATE; ++n) h[n] = 0.f;
    const float bd = bdt[d];
    float sd = 0.f;
    const long base = (long)b * L_SEQ + (long)c * CHUNK;
    for (int i = 0; i < CHUNK; ++i) {
        const long row = base + i;
        float dpv = dpre[row * DINNER + d] + bd;
        float delta = (dpv > 20.f) ? dpv : log1pf(__expf(dpv));
        dpre[row * DINNER + d] = delta;
        sd += delta;
        float dx = delta * xs[row * DINNER + d];
        const u16* sb = ssmb + row * 256;
#pragma unroll
        for (int n = 0; n < NSTATE; ++n)
            h[n] = __builtin_amdgcn_exp2f(delta * a2[n]) * h[n] + dx * bf2f(sb[128 + n]);
    }
    float* hb = hend + ((long)(b * NCHK + c) * DINNER + d) * NSTATE;
#pragma unroll
    for (int n = 0; n < NSTATE; n += 4)
        *(f32x4*)(hb + n) = (f32x4){h[n], h[n + 1], h[n + 2], h[n + 3]};
    sumd[(long)(b * NCHK + c) * DINNER + d] = sd;
}

// ---------------- pass 2: sequential combine across chunks (in place) ----------------
// hend[b][c][d][n] is replaced by the carry-IN state for chunk c.
__global__ __launch_bounds__(256) void scan2_kernel(float* __restrict__ hend,
                                                    const float* __restrict__ sumd,
                                                    const float* __restrict__ Am) {
    const long idx = (long)blockIdx.x * 256 + threadIdx.x;  // B*DINNER*NSTATE = 131072
    const int n = (int)(idx & 15);
    const int d = (int)((idx >> 4) & (DINNER - 1));
    const int b = (int)(idx >> 16);
    const float a2 = Am[d * NSTATE + n] * 1.4426950408889634f;
    float carry = 0.f;
    for (int c = 0; c < NCHK; ++c) {
        const long soff = (long)(b * NCHK + c) * DINNER + d;
        const long hoff = soff * NSTATE + n;
        float he = hend[hoff];
        float P = __builtin_amdgcn_exp2f(a2 * sumd[soff]);
        hend[hoff] = carry;
        carry = he + P * carry;
    }
}

// ---------------- pass 3: re-scan with carry-in; fuses y, Dp*xs, gate-SiLU ----------------
__global__ __launch_bounds__(256) void scan3_kernel(const float* __restrict__ delta_,
                                                    const float* __restrict__ xs,
                                                    const u16* __restrict__ ssmb,
                                                    const u16* __restrict__ xz,
                                                    const float* __restrict__ Am,
                                                    const float* __restrict__ Dp,
                                                    const float* __restrict__ hinit,
                                                    u16* __restrict__ yb) {
    const int d = blockIdx.x * 256 + threadIdx.x;
    const int c = blockIdx.y;
    const int b = blockIdx.z;
    float a2[NSTATE];
#pragma unroll
    for (int n = 0; n < NSTATE; ++n) a2[n] = Am[d * NSTATE + n] * 1.4426950408889634f;
    float h[NSTATE];
    const float* hb = hinit + ((long)(b * NCHK + c) * DINNER + d) * NSTATE;
#pragma unroll
    for (int n = 0; n < NSTATE; n += 4) {
        f32x4 hv = *(const f32x4*)(hb + n);
        h[n] = hv[0]; h[n + 1] = hv[1]; h[n + 2] = hv[2]; h[n + 3] = hv[3];
    }
    const float dp = Dp[d];
    const long base = (long)b * L_SEQ + (long)c * CHUNK;
    for (int i = 0; i < CHUNK; ++i) {
        const long row = base + i;
        float delta = delta_[row * DINNER + d];
        float xt = xs[row * DINNER + d];
        float dx = delta * xt;
        const u16* sb = ssmb + row * 256;
        float y = 0.f;
#pragma unroll
        for (int n = 0; n < NSTATE; ++n) {
            float Bn = bf2f(sb[128 + n]);
            float Cn = bf2f(sb[144 + n]);
            h[n] = __builtin_amdgcn_exp2f(delta * a2[n]) * h[n] + dx * Bn;
            y = fmaf(h[n], Cn, y);
        }
        float g = bf2f(xz[row * (2 * DINNER) + DINNER + d]);
        float yv = (y + dp * xt) * (g / (1.f + __expf(-g)));
        yb[row * DINNER + d] = f2bf(yv);
    }
}

// ---------------- gated MLP activation: act = yy * silu(g) ----------------
__global__ __launch_bounds__(256) void gated_act_kernel(const u16* __restrict__ gy,
                                                        u16* __restrict__ actb) {
    long i = ((long)blockIdx.x * 256 + threadIdx.x) * 8;  // over MROWS*8192
    long m = i >> 13;
    long f = i & 8191;
    const u16* gp = gy + m * 16384 + f;
    union { uint4 v; u16 u[8]; } gu, yu, ob;
    gu.v = *(const uint4*)gp;
    yu.v = *(const uint4*)(gp + 8192);
#pragma unroll
    for (int j = 0; j < 8; ++j) {
        float g = bf2f(gu.u[j]);
        float yv = bf2f(yu.u[j]);
        ob.u[j] = f2bf(yv * (g / (1.f + __expf(-g))));
    }
    *(uint4*)(actb + i) = ob.v;
}

extern "C" void kernel_launch(void* const* d_in, const int* in_sizes, int n_in,
                              void* d_out, int out_size, void* d_ws, size_t ws_size,
                              hipStream_t stream) {
    const float* hidden = (const float*)d_in[0];
    const float* ln1w   = (const float*)d_in[1];
    const float* ln1b   = (const float*)d_in[2];
    const float* W_in   = (const float*)d_in[3];
    const float* conv_w = (const float*)d_in[4];
    const float* conv_b = (const float*)d_in[5];
    const float* W_x    = (const float*)d_in[6];
    const float* W_dt   = (const float*)d_in[7];
    const float* b_dt   = (const float*)d_in[8];
    const float* Amat   = (const float*)d_in[9];
    const float* Dp     = (const float*)d_in[10];
    const float* W_out  = (const float*)d_in[11];
    const float* ln2w   = (const float*)d_in[12];
    const float* ln2b   = (const float*)d_in[13];
    const float* W_fc1  = (const float*)d_in[14];
    const float* W_fc2  = (const float*)d_in[15];
    float* out = (float*)d_out;

    char* ws = (char*)d_ws;
    const size_t SZ67 = 67108864;  // 64 MiB
    u16*   ACT   = (u16*)(ws);                       // 64MB: bf16 activations (reused)
    u16*   WB    = (u16*)(ws + SZ67);                // 64MB: bf16 weights (reused)
    u16*   XZ    = (u16*)(ws + 2 * SZ67);            // 64MB: xz bf16 (4096 x 8192)
    float* XS    = (float*)(ws + 3 * SZ67);          // 64MB: silu(conv) f32 (4096 x 4096)
    float* DELTA = (float*)(ws + 4 * SZ67);          // 64MB: delta_pre f32 -> delta f32
    u16*   SSMB  = (u16*)(ws + 5 * SZ67);            // 2MB : ssm bf16 (4096 x 256)
    float* HS    = (float*)(ws + 5 * SZ67 + 2097152);// 32MB: residual2 f32
    u16*   GY    = XZ;                               // 128MB: spans XZ+XS (4096 x 16384)
    float* HEND  = (float*)WB;                       // 32MB: chunk states (WB free during scan)
    float* SUMD  = (float*)(ws + SZ67 + 33554432);   // 2MB : per-chunk sum(delta)

    // 1) LN1 -> ACT (bf16)
    ln_kernel<<<MROWS, 256, 0, stream>>>(hidden, ln1w, ln1b, ACT);
    // 2) W_in -> WB
    cvt_kernel<<<(int)((8192L * 2048) / 2048), 256, 0, stream>>>(W_in, WB, 8192L * 2048);
    // 3) GEMM1: XZ = ACT @ W_in^T   (M=4096, N=8192, K=2048)
    gemm_bt<1><<<dim3(8192 / 128, MROWS / 128), 256, 0, stream>>>(ACT, WB, nullptr, XZ, nullptr,
                                                                  MROWS, 8192, 2048, 2048);
    // 4) conv + silu -> XS (f32), ACT (bf16)
    conv_silu_kernel<<<dim3(2, MROWS), 256, 0, stream>>>(XZ, conv_w, conv_b, XS, ACT);
    // 5) W_x (160x4096) -> WB zero-padded to 256 rows
    cvt_kernel<<<(int)((256L * 4096) / 2048), 256, 0, stream>>>(W_x, WB, 160L * 4096);
    // 6) GEMM2: SSMB = ACT @ W_x^T  (M=4096, N=256, K=4096), bf16 out
    gemm_bt<1><<<dim3(2, MROWS / 128), 256, 0, stream>>>(ACT, WB, nullptr, SSMB, nullptr,
                                                         MROWS, 256, 4096, 4096);
    // 7) W_dt -> WB
    cvt_kernel<<<(int)((4096L * 128) / 2048), 256, 0, stream>>>(W_dt, WB, 4096L * 128);
    // 8) GEMM3: DELTA = SSMB[:, :128] @ W_dt^T (M=4096, N=4096, K=128, lda=256), f32 out
    gemm_bt<0><<<dim3(4096 / 128, MROWS / 128), 256, 0, stream>>>(SSMB, WB, DELTA, nullptr, nullptr,
                                                                  MROWS, 4096, 128, 256);
    // 9) chunked scan (WB reused as HEND/SUMD scratch)
    scan1_kernel<<<dim3(DINNER / 256, NCHK, 2), 256, 0, stream>>>(DELTA, XS, SSMB, Amat, b_dt,
                                                                  HEND, SUMD);
    scan2_kernel<<<(2 * DINNER * NSTATE) / 256, 256, 0, stream>>>(HEND, SUMD, Amat);
    scan3_kernel<<<dim3(DINNER / 256, NCHK, 2), 256, 0, stream>>>(DELTA, XS, SSMB, XZ, Amat, Dp,
                                                                  HEND, ACT);
    // 10) W_out -> WB
    cvt_kernel<<<(int)((2048L * 4096) / 2048), 256, 0, stream>>>(W_out, WB, 2048L * 4096);
    // 11) GEMM4: HS = ACT @ W_out^T + hidden (M=4096, N=2048, K=4096)
    gemm_bt<2><<<dim3(2048 / 128, MROWS / 128), 256, 0, stream>>>(ACT, WB, HS, nullptr, hidden,
                                                                  MROWS, 2048, 4096, 4096);
    // 12) LN2 -> ACT
    ln_kernel<<<MROWS, 256, 0, stream>>>(HS, ln2w, ln2b, ACT);
    // 13) W_fc1 -> WB
    cvt_kernel<<<(int)((16384L * 2048) / 2048), 256, 0, stream>>>(W_fc1, WB, 16384L * 2048);
    // 14) GEMM5: GY = ACT @ W_fc1^T (M=4096, N=16384, K=2048), bf16 out
    gemm_bt<1><<<dim3(16384 / 128, MROWS / 128), 256, 0, stream>>>(ACT, WB, nullptr, GY, nullptr,
                                                                   MROWS, 16384, 2048, 2048);
    // 15) gated activation -> ACT
    gated_act_kernel<<<(int)((4096L * 8192) / 2048), 256, 0, stream>>>(GY, ACT);
    // 16) W_fc2 -> WB
    cvt_kernel<<<(int)((2048L * 8192) / 2048), 256, 0, stream>>>(W_fc2, WB, 2048L * 8192);
    // 17) GEMM6: out = ACT @ W_fc2^T + HS (M=4096, N=2048, K=8192, lda=8192)
    gemm_bt<2><<<dim3(2048 / 128, MROWS / 128), 256, 0, stream>>>(ACT, WB, out, nullptr, HS,
                                                                  MROWS, 2048, 8192, 8192);
}

// Round 4
// 1252.371 us; speedup vs baseline: 3.3148x; 1.0965x over previous
//
#include <hip/hip_runtime.h>
#include <hip/hip_bf16.h>

typedef unsigned short u16;
typedef unsigned int u32;

#define L_SEQ 2048
#define DMODEL 2048
#define DINNER 4096
#define NSTATE 16
#define MROWS 4096   // B*L
#define CHUNK 32
#define NCHK  64     // L_SEQ / CHUNK

typedef __bf16 bf16x8 __attribute__((ext_vector_type(8)));
typedef float f32x4 __attribute__((ext_vector_type(4)));

__device__ __forceinline__ u16 f2bf(float f) {
    union { float f; u32 u; } v; v.f = f;
    u32 u = v.u;
    u32 r = (u + 0x7fffu + ((u >> 16) & 1u)) >> 16;
    return (u16)r;
}
__device__ __forceinline__ float bf2f(u16 h) {
    union { u32 u; float f; } v; v.u = ((u32)h) << 16;
    return v.f;
}

__device__ __forceinline__ void gload16(const void* g, void* l) {
    __builtin_amdgcn_global_load_lds((const __attribute__((address_space(1))) void*)g,
                                     (__attribute__((address_space(3))) void*)l, 16, 0, 0);
}

// ---------------- f32 -> bf16 conversion (zero-pads tail beyond nsrc) ----------------
__global__ __launch_bounds__(256) void cvt_kernel(const float* __restrict__ src,
                                                  u16* __restrict__ dst, long nsrc) {
    long i = ((long)blockIdx.x * 256 + threadIdx.x) * 8;
    union { uint4 v; u16 u[8]; } o;
    if (i < nsrc) {
        f32x4 a = *(const f32x4*)(src + i);
        f32x4 b = *(const f32x4*)(src + i + 4);
#pragma unroll
        for (int j = 0; j < 4; ++j) { o.u[j] = f2bf(a[j]); o.u[4 + j] = f2bf(b[j]); }
    } else {
#pragma unroll
        for (int j = 0; j < 8; ++j) o.u[j] = 0;
    }
    *(uint4*)(dst + i) = o.v;
}

// ---------------- LayerNorm (D=2048) -> bf16 ----------------
__global__ __launch_bounds__(256) void ln_kernel(const float* __restrict__ in,
                                                 const float* __restrict__ w,
                                                 const float* __restrict__ b,
                                                 u16* __restrict__ out) {
    const long row = blockIdx.x;
    const float* x = in + row * DMODEL;
    const int t = threadIdx.x;
    f32x4 v0 = *(const f32x4*)(x + t * 8);
    f32x4 v1 = *(const f32x4*)(x + t * 8 + 4);
    float s = 0.f, sq = 0.f;
#pragma unroll
    for (int j = 0; j < 4; ++j) {
        s += v0[j] + v1[j];
        sq += v0[j] * v0[j] + v1[j] * v1[j];
    }
#pragma unroll
    for (int off = 32; off > 0; off >>= 1) {
        s += __shfl_down(s, off);
        sq += __shfl_down(sq, off);
    }
    __shared__ float red[8];
    __shared__ float stats[2];
    const int wid = t >> 6, lane = t & 63;
    if (lane == 0) { red[wid] = s; red[4 + wid] = sq; }
    __syncthreads();
    if (t == 0) {
        float S = red[0] + red[1] + red[2] + red[3];
        float Q = red[4] + red[5] + red[6] + red[7];
        float mu = S / (float)DMODEL;
        stats[0] = mu;
        stats[1] = rsqrtf(Q / (float)DMODEL - mu * mu + 1e-5f);
    }
    __syncthreads();
    float mu = stats[0], rstd = stats[1];
    union { uint4 v; u16 u[8]; } o;
#pragma unroll
    for (int j = 0; j < 8; ++j) {
        float xv = (j < 4) ? v0[j] : v1[j - 4];
        o.u[j] = f2bf((xv - mu) * rstd * w[t * 8 + j] + b[t * 8 + j]);
    }
    *(uint4*)(out + row * DMODEL + t * 8) = o.v;
}

// ---------------- 128x128 2-phase GEMM (kept for small-N GEMM2) ----------------
template <int MODE>
__global__ __launch_bounds__(256) void gemm_bt(const u16* __restrict__ A,
                                               const u16* __restrict__ W,
                                               float* __restrict__ Cf,
                                               u16* __restrict__ Cb,
                                               const float* __restrict__ addv,
                                               int M, int N, int K, int lda) {
    __shared__ u16 As[128 * 64];
    __shared__ u16 Bs[128 * 64];
    const int tid = threadIdx.x;
    const int wid = tid >> 6;
    const int lane = tid & 63;
    const int m0 = blockIdx.y << 7;
    const int n0 = blockIdx.x << 7;
    const int wr = (wid >> 1) << 6;
    const int wc = (wid & 1) << 6;
    const int l15 = lane & 15;
    const int lhi = lane >> 4;

    f32x4 acc[4][4];
#pragma unroll
    for (int i = 0; i < 4; ++i)
#pragma unroll
        for (int j = 0; j < 4; ++j) acc[i][j] = (f32x4){0.f, 0.f, 0.f, 0.f};

    const int srow = (wid << 3) + (lane >> 3);
    const int scol = (lane & 7) << 3;

    const u16* aBase = A + (long)(m0 + srow) * lda + scol;
    const u16* bBase = W + (long)(n0 + srow) * (long)K + scol;

    for (int k0 = 0; k0 < K; k0 += 64) {
#pragma unroll
        for (int i = 0; i < 4; ++i) {
            gload16(aBase + (long)(i * 32) * lda + k0, &As[((i << 5) + (wid << 3)) << 6]);
            gload16(bBase + (long)(i * 32) * K + k0, &Bs[((i << 5) + (wid << 3)) << 6]);
        }
        __syncthreads();
#pragma unroll
        for (int kk = 0; kk < 64; kk += 32) {
            bf16x8 af[4], bfr[4];
#pragma unroll
            for (int i = 0; i < 4; ++i)
                af[i] = *(const bf16x8*)&As[((wr + (i << 4) + l15) << 6) + kk + (lhi << 3)];
#pragma unroll
            for (int j = 0; j < 4; ++j)
                bfr[j] = *(const bf16x8*)&Bs[((wc + (j << 4) + l15) << 6) + kk + (lhi << 3)];
#pragma unroll
            for (int i = 0; i < 4; ++i)
#pragma unroll
                for (int j = 0; j < 4; ++j)
                    acc[i][j] = __builtin_amdgcn_mfma_f32_16x16x32_bf16(af[i], bfr[j], acc[i][j], 0, 0, 0);
        }
        __syncthreads();
    }

#pragma unroll
    for (int i = 0; i < 4; ++i) {
#pragma unroll
        for (int j = 0; j < 4; ++j) {
#pragma unroll
            for (int r = 0; r < 4; ++r) {
                int row = m0 + wr + (i << 4) + (lhi << 2) + r;
                int col = n0 + wc + (j << 4) + l15;
                long idx = (long)row * N + col;
                float v = acc[i][j][r];
                if (MODE == 2) v += addv[idx];
                if (MODE == 1) Cb[idx] = f2bf(v);
                else Cf[idx] = v;
            }
        }
    }
}

// ---------------- 256x256 8-wave pipelined GEMM, BK=32, ring-4 LDS ----------------
// C[M,N] = A[M,K(lda)] @ W[N,K]^T. MODE as gemm_bt. Requires M%256==0, N%256==0, K%128==0.
// Schedule: 2 phases/K-tile {ds_read; stage; barrier; setprio(1); 16 MFMA; setprio(0); barrier},
// stages for K-tile t+3 issued during t (ring of 4 buffers -> no overwrite hazard),
// counted vmcnt(8) at iteration end (never 0 in steady state).
// LDS read swizzle c16 ^= (row>>1)&3, inverse-applied to global source (gload_lds is linear).
template <int MODE>
__global__ __launch_bounds__(512, 2) void gemm8(const u16* __restrict__ A,
                                                const u16* __restrict__ W,
                                                float* __restrict__ Cf,
                                                u16* __restrict__ Cb,
                                                const float* __restrict__ addv,
                                                int M, int N, int K, int lda) {
    __shared__ u16 lds[4][2][256 * 32];   // [buf][A=0/B=1][row*32 + col]
    const int tid = threadIdx.x;
    const int wid = tid >> 6;        // 0..7
    const int lane = tid & 63;
    const int wr = wid >> 2;         // 0..1 : M-half (128 rows)
    const int wc = wid & 3;          // 0..3 : N-quarter (64 cols)
    const int l15 = lane & 15;
    const int lhi = lane >> 4;       // 0..3
    const int sw = (l15 >> 1) & 3;   // read-side swizzle index

    // T1: bijective XCD-aware block swizzle
    const int nwg = gridDim.x * gridDim.y;
    const int flat = blockIdx.y * gridDim.x + blockIdx.x;
    const int q8 = nwg >> 3, r8 = nwg & 7;
    const int xcd = flat & 7, lid = flat >> 3;
    const int swz = (xcd < r8 ? xcd * (q8 + 1) : r8 * (q8 + 1) + (xcd - r8) * q8) + lid;
    const int m0 = (swz / gridDim.x) << 8;
    const int n0 = (swz % gridDim.x) << 8;

    // staging geometry: per gload, wave covers 16 rows x 64B; 2 rounds each for A,B
    const int srow = lane >> 2;                          // row within 16-row slab
    const int gc16 = (lane & 3) ^ ((lane >> 3) & 3);     // pre-swizzled source column slot

    f32x4 acc[8][4];
#pragma unroll
    for (int i = 0; i < 8; ++i)
#pragma unroll
        for (int j = 0; j < 4; ++j) acc[i][j] = (f32x4){0.f, 0.f, 0.f, 0.f};

#define STAGE_A(t, j)                                                                   \
    gload16(A + (long)(m0 + (j) * 128 + wid * 16 + srow) * lda + (long)(t) * 32 + gc16 * 8, \
            &lds[(t) & 3][0][((j) * 128 + wid * 16) * 32])
#define STAGE_B(t, j)                                                                   \
    gload16(W + (long)(n0 + (j) * 128 + wid * 16 + srow) * (long)K + (long)(t) * 32 + gc16 * 8, \
            &lds[(t) & 3][1][((j) * 128 + wid * 16) * 32])

    // prologue: stage K-tiles 0,1,2 (12 loads/thread)
    STAGE_A(0, 0); STAGE_A(0, 1); STAGE_B(0, 0); STAGE_B(0, 1);
    STAGE_A(1, 0); STAGE_A(1, 1); STAGE_B(1, 0); STAGE_B(1, 1);
    STAGE_A(2, 0); STAGE_A(2, 1); STAGE_B(2, 0); STAGE_B(2, 1);
    asm volatile("s_waitcnt vmcnt(8)" ::: "memory");   // K-tile 0 resident
    __builtin_amdgcn_s_barrier();
    __builtin_amdgcn_sched_barrier(0);

    const int nt = K >> 5;
    for (int t = 0; t < nt; ++t) {
        const u16* Ab = &lds[t & 3][0][0];
        const u16* Bb = &lds[t & 3][1][0];
        bf16x8 afrg[4], bfrg[4];
        // ---- phase 1: A frags 0-3 + B frags 0-3 ----
#pragma unroll
        for (int f = 0; f < 4; ++f)
            afrg[f] = *(const bf16x8*)&Ab[(wr * 128 + f * 16 + l15) * 32 + ((lhi ^ sw) << 3)];
#pragma unroll
        for (int f = 0; f < 4; ++f)
            bfrg[f] = *(const bf16x8*)&Bb[(wc * 64 + f * 16 + l15) * 32 + ((lhi ^ sw) << 3)];
        if (t + 3 < nt) { STAGE_A(t + 3, 0); STAGE_A(t + 3, 1); }
        __builtin_amdgcn_s_barrier();
        __builtin_amdgcn_s_setprio(1);
#pragma unroll
        for (int i = 0; i < 4; ++i)
#pragma unroll
            for (int j = 0; j < 4; ++j)
                acc[i][j] = __builtin_amdgcn_mfma_f32_16x16x32_bf16(afrg[i], bfrg[j], acc[i][j], 0, 0, 0);
        __builtin_amdgcn_s_setprio(0);
        __builtin_amdgcn_s_barrier();
        // ---- phase 2: A frags 4-7 (B reused) ----
#pragma unroll
        for (int f = 0; f < 4; ++f)
            afrg[f] = *(const bf16x8*)&Ab[(wr * 128 + (f + 4) * 16 + l15) * 32 + ((lhi ^ sw) << 3)];
        if (t + 3 < nt) { STAGE_B(t + 3, 0); STAGE_B(t + 3, 1); }
        __builtin_amdgcn_s_barrier();
        __builtin_amdgcn_s_setprio(1);
#pragma unroll
        for (int i = 0; i < 4; ++i)
#pragma unroll
            for (int j = 0; j < 4; ++j)
                acc[i + 4][j] = __builtin_amdgcn_mfma_f32_16x16x32_bf16(afrg[i], bfrg[j], acc[i + 4][j], 0, 0, 0);
        __builtin_amdgcn_s_setprio(0);
        // ---- end of iteration: ensure K-tile t+1 resident for all waves ----
        const int rem = nt - 2 - t;
        if (rem >= 2)      { asm volatile("s_waitcnt vmcnt(8)" ::: "memory"); }
        else if (rem == 1) { asm volatile("s_waitcnt vmcnt(4)" ::: "memory"); }
        else if (rem == 0) { asm volatile("s_waitcnt vmcnt(0)" ::: "memory"); }
        __builtin_amdgcn_s_barrier();
        __builtin_amdgcn_sched_barrier(0);
    }
#undef STAGE_A
#undef STAGE_B

#pragma unroll
    for (int i = 0; i < 8; ++i) {
#pragma unroll
        for (int j = 0; j < 4; ++j) {
#pragma unroll
            for (int r = 0; r < 4; ++r) {
                int row = m0 + wr * 128 + i * 16 + lhi * 4 + r;
                int col = n0 + wc * 64 + j * 16 + l15;
                long idx = (long)row * N + col;
                float v = acc[i][j][r];
                if (MODE == 2) v += addv[idx];
                if (MODE == 1) Cb[idx] = f2bf(v);
                else Cf[idx] = v;
            }
        }
    }
}

// ---------------- causal depthwise conv (K=4) + SiLU ----------------
__global__ __launch_bounds__(256) void conv_silu_kernel(const u16* __restrict__ xz,
                                                        const float* __restrict__ cw,
                                                        const float* __restrict__ cb,
                                                        float* __restrict__ xs_out,
                                                        u16* __restrict__ act_out) {
    const int d0 = (blockIdx.x * 256 + threadIdx.x) * 8;
    const int bl = blockIdx.y;
    const int l = bl & (L_SEQ - 1);
    float acc[8];
    float wt[8][4];
#pragma unroll
    for (int j = 0; j < 8; ++j) {
        f32x4 wj = *(const f32x4*)(cw + (d0 + j) * 4);
        wt[j][0] = wj[0]; wt[j][1] = wj[1]; wt[j][2] = wj[2]; wt[j][3] = wj[3];
        acc[j] = cb[d0 + j];
    }
#pragma unroll
    for (int k = 0; k < 4; ++k) {
        int ls = l + k - 3;
        if (ls >= 0) {
            union { uint4 v; u16 u[8]; } xv;
            xv.v = *(const uint4*)(xz + (long)(bl + k - 3) * (2 * DINNER) + d0);
#pragma unroll
            for (int j = 0; j < 8; ++j) acc[j] = fmaf(bf2f(xv.u[j]), wt[j][k], acc[j]);
        }
    }
    union { uint4 v; u16 u[8]; } ob;
    f32x4 o0, o1;
#pragma unroll
    for (int j = 0; j < 8; ++j) {
        float c = acc[j];
        float sv = c / (1.f + __expf(-c));
        if (j < 4) o0[j] = sv; else o1[j - 4] = sv;
        ob.u[j] = f2bf(sv);
    }
    long orow = (long)bl * DINNER + d0;
    *(f32x4*)(xs_out + orow) = o0;
    *(f32x4*)(xs_out + orow + 4) = o1;
    *(uint4*)(act_out + orow) = ob.v;
}

// ---------------- SSM chunked scan pass 1 ----------------
__global__ __launch_bounds__(256) void scan1_kernel(float* __restrict__ dpre,
                                                    const float* __restrict__ xs,
                                                    const u16* __restrict__ ssmb,
                                                    const float* __restrict__ Am,
                                                    const float* __restrict__ bdt,
                                                    float* __restrict__ hend,
                                                    float* __restrict__ sumd) {
    const int d = blockIdx.x * 256 + threadIdx.x;
    const int c = blockIdx.y;
    const int b = blockIdx.z;
    float a2[NSTATE];
#pragma unroll
    for (int n = 0; n < NSTATE; ++n) a2[n] = Am[d * NSTATE + n] * 1.4426950408889634f;
    float h[NSTATE];
#pragma unroll
    for (int n = 0; n < NSTATE; ++n) h[n] = 0.f;
    const float bd = bdt[d];
    float sd = 0.f;
    const long base = (long)b * L_SEQ + (long)c * CHUNK;
    for (int i = 0; i < CHUNK; ++i) {
        const long row = base + i;
        float dpv = dpre[row * DINNER + d] + bd;
        float delta = (dpv > 20.f) ? dpv : log1pf(__expf(dpv));
        dpre[row * DINNER + d] = delta;
        sd += delta;
        float dx = delta * xs[row * DINNER + d];
        const u16* sb = ssmb + row * 256;
#pragma unroll
        for (int n = 0; n < NSTATE; ++n)
            h[n] = __builtin_amdgcn_exp2f(delta * a2[n]) * h[n] + dx * bf2f(sb[128 + n]);
    }
    float* hb = hend + ((long)(b * NCHK + c) * DINNER + d) * NSTATE;
#pragma unroll
    for (int n = 0; n < NSTATE; n += 4)
        *(f32x4*)(hb + n) = (f32x4){h[n], h[n + 1], h[n + 2], h[n + 3]};
    sumd[(long)(b * NCHK + c) * DINNER + d] = sd;
}

// ---------------- pass 2: sequential combine across chunks (in place) ----------------
__global__ __launch_bounds__(256) void scan2_kernel(float* __restrict__ hend,
                                                    const float* __restrict__ sumd,
                                                    const float* __restrict__ Am) {
    const long idx = (long)blockIdx.x * 256 + threadIdx.x;
    const int n = (int)(idx & 15);
    const int d = (int)((idx >> 4) & (DINNER - 1));
    const int b = (int)(idx >> 16);
    const float a2 = Am[d * NSTATE + n] * 1.4426950408889634f;
    float carry = 0.f;
    for (int c = 0; c < NCHK; ++c) {
        const long soff = (long)(b * NCHK + c) * DINNER + d;
        const long hoff = soff * NSTATE + n;
        float he = hend[hoff];
        float P = __builtin_amdgcn_exp2f(a2 * sumd[soff]);
        hend[hoff] = carry;
        carry = he + P * carry;
    }
}

// ---------------- pass 3: re-scan with carry-in; fuses y, Dp*xs, gate-SiLU ----------------
__global__ __launch_bounds__(256) void scan3_kernel(const float* __restrict__ delta_,
                                                    const float* __restrict__ xs,
                                                    const u16* __restrict__ ssmb,
                                                    const u16* __restrict__ xz,
                                                    const float* __restrict__ Am,
                                                    const float* __restrict__ Dp,
                                                    const float* __restrict__ hinit,
                                                    u16* __restrict__ yb) {
    const int d = blockIdx.x * 256 + threadIdx.x;
    const int c = blockIdx.y;
    const int b = blockIdx.z;
    float a2[NSTATE];
#pragma unroll
    for (int n = 0; n < NSTATE; ++n) a2[n] = Am[d * NSTATE + n] * 1.4426950408889634f;
    float h[NSTATE];
    const float* hb = hinit + ((long)(b * NCHK + c) * DINNER + d) * NSTATE;
#pragma unroll
    for (int n = 0; n < NSTATE; n += 4) {
        f32x4 hv = *(const f32x4*)(hb + n);
        h[n] = hv[0]; h[n + 1] = hv[1]; h[n + 2] = hv[2]; h[n + 3] = hv[3];
    }
    const float dp = Dp[d];
    const long base = (long)b * L_SEQ + (long)c * CHUNK;
    for (int i = 0; i < CHUNK; ++i) {
        const long row = base + i;
        float delta = delta_[row * DINNER + d];
        float xt = xs[row * DINNER + d];
        float dx = delta * xt;
        const u16* sb = ssmb + row * 256;
        float y = 0.f;
#pragma unroll
        for (int n = 0; n < NSTATE; ++n) {
            float Bn = bf2f(sb[128 + n]);
            float Cn = bf2f(sb[144 + n]);
            h[n] = __builtin_amdgcn_exp2f(delta * a2[n]) * h[n] + dx * Bn;
            y = fmaf(h[n], Cn, y);
        }
        float g = bf2f(xz[row * (2 * DINNER) + DINNER + d]);
        float yv = (y + dp * xt) * (g / (1.f + __expf(-g)));
        yb[row * DINNER + d] = f2bf(yv);
    }
}

// ---------------- gated MLP activation: act = yy * silu(g) ----------------
__global__ __launch_bounds__(256) void gated_act_kernel(const u16* __restrict__ gy,
                                                        u16* __restrict__ actb) {
    long i = ((long)blockIdx.x * 256 + threadIdx.x) * 8;
    long m = i >> 13;
    long f = i & 8191;
    const u16* gp = gy + m * 16384 + f;
    union { uint4 v; u16 u[8]; } gu, yu, ob;
    gu.v = *(const uint4*)gp;
    yu.v = *(const uint4*)(gp + 8192);
#pragma unroll
    for (int j = 0; j < 8; ++j) {
        float g = bf2f(gu.u[j]);
        float yv = bf2f(yu.u[j]);
        ob.u[j] = f2bf(yv * (g / (1.f + __expf(-g))));
    }
    *(uint4*)(actb + i) = ob.v;
}

extern "C" void kernel_launch(void* const* d_in, const int* in_sizes, int n_in,
                              void* d_out, int out_size, void* d_ws, size_t ws_size,
                              hipStream_t stream) {
    const float* hidden = (const float*)d_in[0];
    const float* ln1w   = (const float*)d_in[1];
    const float* ln1b   = (const float*)d_in[2];
    const float* W_in   = (const float*)d_in[3];
    const float* conv_w = (const float*)d_in[4];
    const float* conv_b = (const float*)d_in[5];
    const float* W_x    = (const float*)d_in[6];
    const float* W_dt   = (const float*)d_in[7];
    const float* b_dt   = (const float*)d_in[8];
    const float* Amat   = (const float*)d_in[9];
    const float* Dp     = (const float*)d_in[10];
    const float* W_out  = (const float*)d_in[11];
    const float* ln2w   = (const float*)d_in[12];
    const float* ln2b   = (const float*)d_in[13];
    const float* W_fc1  = (const float*)d_in[14];
    const float* W_fc2  = (const float*)d_in[15];
    float* out = (float*)d_out;

    char* ws = (char*)d_ws;
    const size_t SZ67 = 67108864;  // 64 MiB
    u16*   ACT   = (u16*)(ws);
    u16*   WB    = (u16*)(ws + SZ67);
    u16*   XZ    = (u16*)(ws + 2 * SZ67);
    float* XS    = (float*)(ws + 3 * SZ67);
    float* DELTA = (float*)(ws + 4 * SZ67);
    u16*   SSMB  = (u16*)(ws + 5 * SZ67);
    float* HS    = (float*)(ws + 5 * SZ67 + 2097152);
    u16*   GY    = XZ;
    float* HEND  = (float*)WB;
    float* SUMD  = (float*)(ws + SZ67 + 33554432);

    // 1) LN1 -> ACT (bf16)
    ln_kernel<<<MROWS, 256, 0, stream>>>(hidden, ln1w, ln1b, ACT);
    // 2) W_in -> WB
    cvt_kernel<<<(int)((8192L * 2048) / 2048), 256, 0, stream>>>(W_in, WB, 8192L * 2048);
    // 3) GEMM1: XZ = ACT @ W_in^T   (M=4096, N=8192, K=2048)
    gemm8<1><<<dim3(8192 / 256, MROWS / 256), 512, 0, stream>>>(ACT, WB, nullptr, XZ, nullptr,
                                                                MROWS, 8192, 2048, 2048);
    // 4) conv + silu -> XS (f32), ACT (bf16)
    conv_silu_kernel<<<dim3(2, MROWS), 256, 0, stream>>>(XZ, conv_w, conv_b, XS, ACT);
    // 5) W_x (160x4096) -> WB zero-padded to 256 rows
    cvt_kernel<<<(int)((256L * 4096) / 2048), 256, 0, stream>>>(W_x, WB, 160L * 4096);
    // 6) GEMM2: SSMB = ACT @ W_x^T  (M=4096, N=256, K=4096), bf16 out (old 128^2 kernel)
    gemm_bt<1><<<dim3(2, MROWS / 128), 256, 0, stream>>>(ACT, WB, nullptr, SSMB, nullptr,
                                                         MROWS, 256, 4096, 4096);
    // 7) W_dt -> WB
    cvt_kernel<<<(int)((4096L * 128) / 2048), 256, 0, stream>>>(W_dt, WB, 4096L * 128);
    // 8) GEMM3: DELTA = SSMB[:, :128] @ W_dt^T (M=4096, N=4096, K=128, lda=256)
    gemm8<0><<<dim3(4096 / 256, MROWS / 256), 512, 0, stream>>>(SSMB, WB, DELTA, nullptr, nullptr,
                                                                MROWS, 4096, 128, 256);
    // 9) chunked scan (WB reused as HEND/SUMD scratch)
    scan1_kernel<<<dim3(DINNER / 256, NCHK, 2), 256, 0, stream>>>(DELTA, XS, SSMB, Amat, b_dt,
                                                                  HEND, SUMD);
    scan2_kernel<<<(2 * DINNER * NSTATE) / 256, 256, 0, stream>>>(HEND, SUMD, Amat);
    scan3_kernel<<<dim3(DINNER / 256, NCHK, 2), 256, 0, stream>>>(DELTA, XS, SSMB, XZ, Amat, Dp,
                                                                  HEND, ACT);
    // 10) W_out -> WB
    cvt_kernel<<<(int)((2048L * 4096) / 2048), 256, 0, stream>>>(W_out, WB, 2048L * 4096);
    // 11) GEMM4: HS = ACT @ W_out^T + hidden (M=4096, N=2048, K=4096)
    gemm8<2><<<dim3(2048 / 256, MROWS / 256), 512, 0, stream>>>(ACT, WB, HS, nullptr, hidden,
                                                                MROWS, 2048, 4096, 4096);
    // 12) LN2 -> ACT
    ln_kernel<<<MROWS, 256, 0, stream>>>(HS, ln2w, ln2b, ACT);
    // 13) W_fc1 -> WB
    cvt_kernel<<<(int)((16384L * 2048) / 2048), 256, 0, stream>>>(W_fc1, WB, 16384L * 2048);
    // 14) GEMM5: GY = ACT @ W_fc1^T (M=4096, N=16384, K=2048), bf16 out
    gemm8<1><<<dim3(16384 / 256, MROWS / 256), 512, 0, stream>>>(ACT, WB, nullptr, GY, nullptr,
                                                                 MROWS, 16384, 2048, 2048);
    // 15) gated activation -> ACT
    gated_act_kernel<<<(int)((4096L * 8192) / 2048), 256, 0, stream>>>(GY, ACT);
    // 16) W_fc2 -> WB
    cvt_kernel<<<(int)((2048L * 8192) / 2048), 256, 0, stream>>>(W_fc2, WB, 2048L * 8192);
    // 17) GEMM6: out = ACT @ W_fc2^T + HS (M=4096, N=2048, K=8192, lda=8192)
    gemm8<2><<<dim3(2048 / 256, MROWS / 256), 512, 0, stream>>>(ACT, WB, out, nullptr, HS,
                                                                MROWS, 2048, 8192, 8192);
}

// Round 5
// 1089.761 us; speedup vs baseline: 3.8095x; 1.1492x over previous
//
#include <hip/hip_runtime.h>
#include <hip/hip_bf16.h>

typedef unsigned short u16;
typedef unsigned int u32;

#define L_SEQ 2048
#define DMODEL 2048
#define DINNER 4096
#define NSTATE 16
#define MROWS 4096   // B*L
#define CHUNK 32
#define NCHK  64     // L_SEQ / CHUNK

typedef __bf16 bf16x8 __attribute__((ext_vector_type(8)));
typedef float f32x4 __attribute__((ext_vector_type(4)));

__device__ __forceinline__ u16 f2bf(float f) {
    union { float f; u32 u; } v; v.f = f;
    u32 u = v.u;
    u32 r = (u + 0x7fffu + ((u >> 16) & 1u)) >> 16;
    return (u16)r;
}
__device__ __forceinline__ float bf2f(u16 h) {
    union { u32 u; float f; } v; v.u = ((u32)h) << 16;
    return v.f;
}

__device__ __forceinline__ void gload16(const void* g, void* l) {
    __builtin_amdgcn_global_load_lds((const __attribute__((address_space(1))) void*)g,
                                     (__attribute__((address_space(3))) void*)l, 16, 0, 0);
}

// ---------------- f32 -> bf16 conversion (zero-pads tail beyond nsrc) ----------------
__global__ __launch_bounds__(256) void cvt_kernel(const float* __restrict__ src,
                                                  u16* __restrict__ dst, long nsrc) {
    long i = ((long)blockIdx.x * 256 + threadIdx.x) * 8;
    union { uint4 v; u16 u[8]; } o;
    if (i < nsrc) {
        f32x4 a = *(const f32x4*)(src + i);
        f32x4 b = *(const f32x4*)(src + i + 4);
#pragma unroll
        for (int j = 0; j < 4; ++j) { o.u[j] = f2bf(a[j]); o.u[4 + j] = f2bf(b[j]); }
    } else {
#pragma unroll
        for (int j = 0; j < 8; ++j) o.u[j] = 0;
    }
    *(uint4*)(dst + i) = o.v;
}

// ---------------- LayerNorm (D=2048) -> bf16 ----------------
__global__ __launch_bounds__(256) void ln_kernel(const float* __restrict__ in,
                                                 const float* __restrict__ w,
                                                 const float* __restrict__ b,
                                                 u16* __restrict__ out) {
    const long row = blockIdx.x;
    const float* x = in + row * DMODEL;
    const int t = threadIdx.x;
    f32x4 v0 = *(const f32x4*)(x + t * 8);
    f32x4 v1 = *(const f32x4*)(x + t * 8 + 4);
    float s = 0.f, sq = 0.f;
#pragma unroll
    for (int j = 0; j < 4; ++j) {
        s += v0[j] + v1[j];
        sq += v0[j] * v0[j] + v1[j] * v1[j];
    }
#pragma unroll
    for (int off = 32; off > 0; off >>= 1) {
        s += __shfl_down(s, off);
        sq += __shfl_down(sq, off);
    }
    __shared__ float red[8];
    __shared__ float stats[2];
    const int wid = t >> 6, lane = t & 63;
    if (lane == 0) { red[wid] = s; red[4 + wid] = sq; }
    __syncthreads();
    if (t == 0) {
        float S = red[0] + red[1] + red[2] + red[3];
        float Q = red[4] + red[5] + red[6] + red[7];
        float mu = S / (float)DMODEL;
        stats[0] = mu;
        stats[1] = rsqrtf(Q / (float)DMODEL - mu * mu + 1e-5f);
    }
    __syncthreads();
    float mu = stats[0], rstd = stats[1];
    union { uint4 v; u16 u[8]; } o;
#pragma unroll
    for (int j = 0; j < 8; ++j) {
        float xv = (j < 4) ? v0[j] : v1[j - 4];
        o.u[j] = f2bf((xv - mu) * rstd * w[t * 8 + j] + b[t * 8 + j]);
    }
    *(uint4*)(out + row * DMODEL + t * 8) = o.v;
}

// ---------------- 128x128 2-phase GEMM (used for small-N GEMM2, split-K capable) ----------------
// koff = blockIdx.z * K; f32 output offset by blockIdx.z * M * N.
template <int MODE>
__global__ __launch_bounds__(256) void gemm_bt(const u16* __restrict__ A,
                                               const u16* __restrict__ W,
                                               float* __restrict__ Cf,
                                               u16* __restrict__ Cb,
                                               const float* __restrict__ addv,
                                               int M, int N, int K, int lda, int ldb) {
    __shared__ u16 As[128 * 64];
    __shared__ u16 Bs[128 * 64];
    const int tid = threadIdx.x;
    const int wid = tid >> 6;
    const int lane = tid & 63;
    const int m0 = blockIdx.y << 7;
    const int n0 = blockIdx.x << 7;
    const long koff = (long)blockIdx.z * K;
    const long zoff = (long)blockIdx.z * M * N;
    const int wr = (wid >> 1) << 6;
    const int wc = (wid & 1) << 6;
    const int l15 = lane & 15;
    const int lhi = lane >> 4;

    f32x4 acc[4][4];
#pragma unroll
    for (int i = 0; i < 4; ++i)
#pragma unroll
        for (int j = 0; j < 4; ++j) acc[i][j] = (f32x4){0.f, 0.f, 0.f, 0.f};

    const int srow = (wid << 3) + (lane >> 3);
    const int scol = (lane & 7) << 3;

    const u16* aBase = A + (long)(m0 + srow) * lda + scol + koff;
    const u16* bBase = W + (long)(n0 + srow) * (long)ldb + scol + koff;

    for (int k0 = 0; k0 < K; k0 += 64) {
#pragma unroll
        for (int i = 0; i < 4; ++i) {
            gload16(aBase + (long)(i * 32) * lda + k0, &As[((i << 5) + (wid << 3)) << 6]);
            gload16(bBase + (long)(i * 32) * ldb + k0, &Bs[((i << 5) + (wid << 3)) << 6]);
        }
        __syncthreads();
#pragma unroll
        for (int kk = 0; kk < 64; kk += 32) {
            bf16x8 af[4], bfr[4];
#pragma unroll
            for (int i = 0; i < 4; ++i)
                af[i] = *(const bf16x8*)&As[((wr + (i << 4) + l15) << 6) + kk + (lhi << 3)];
#pragma unroll
            for (int j = 0; j < 4; ++j)
                bfr[j] = *(const bf16x8*)&Bs[((wc + (j << 4) + l15) << 6) + kk + (lhi << 3)];
#pragma unroll
            for (int i = 0; i < 4; ++i)
#pragma unroll
                for (int j = 0; j < 4; ++j)
                    acc[i][j] = __builtin_amdgcn_mfma_f32_16x16x32_bf16(af[i], bfr[j], acc[i][j], 0, 0, 0);
        }
        __syncthreads();
    }

#pragma unroll
    for (int i = 0; i < 4; ++i) {
#pragma unroll
        for (int j = 0; j < 4; ++j) {
#pragma unroll
            for (int r = 0; r < 4; ++r) {
                int row = m0 + wr + (i << 4) + (lhi << 2) + r;
                int col = n0 + wc + (j << 4) + l15;
                long idx = (long)row * N + col;
                float v = acc[i][j][r];
                if (MODE == 2) v += addv[idx];
                if (MODE == 1) Cb[idx] = f2bf(v);
                else Cf[zoff + idx] = v;
            }
        }
    }
}

// ---------------- 256x256 8-wave pipelined GEMM, BK=32, ring-4 LDS, split-K capable ----------------
// C[M,N] = A[M,koff:koff+K(lda)] @ W[N,*(ldb)]^T. MODE as gemm_bt.
template <int MODE>
__global__ __launch_bounds__(512, 2) void gemm8(const u16* __restrict__ A,
                                                const u16* __restrict__ W,
                                                float* __restrict__ Cf,
                                                u16* __restrict__ Cb,
                                                const float* __restrict__ addv,
                                                int M, int N, int K, int lda, int ldb) {
    __shared__ u16 lds[4][2][256 * 32];   // [buf][A=0/B=1][row*32 + col]
    const int tid = threadIdx.x;
    const int wid = tid >> 6;        // 0..7
    const int lane = tid & 63;
    const int wr = wid >> 2;         // 0..1 : M-half (128 rows)
    const int wc = wid & 3;          // 0..3 : N-quarter (64 cols)
    const int l15 = lane & 15;
    const int lhi = lane >> 4;       // 0..3
    const int sw = (l15 >> 1) & 3;   // read-side swizzle index
    const long koff = (long)blockIdx.z * K;
    const long zoff = (long)blockIdx.z * M * N;

    // T1: bijective XCD-aware block swizzle (x,y plane only)
    const int nwg = gridDim.x * gridDim.y;
    const int flat = blockIdx.y * gridDim.x + blockIdx.x;
    const int q8 = nwg >> 3, r8 = nwg & 7;
    const int xcd = flat & 7, lid = flat >> 3;
    const int swz = (xcd < r8 ? xcd * (q8 + 1) : r8 * (q8 + 1) + (xcd - r8) * q8) + lid;
    const int m0 = (swz / gridDim.x) << 8;
    const int n0 = (swz % gridDim.x) << 8;

    const int srow = lane >> 2;                          // row within 16-row slab
    const int gc16 = (lane & 3) ^ ((lane >> 3) & 3);     // pre-swizzled source column slot

    f32x4 acc[8][4];
#pragma unroll
    for (int i = 0; i < 8; ++i)
#pragma unroll
        for (int j = 0; j < 4; ++j) acc[i][j] = (f32x4){0.f, 0.f, 0.f, 0.f};

#define STAGE_A(t, j)                                                                              \
    gload16(A + (long)(m0 + (j) * 128 + wid * 16 + srow) * lda + koff + (long)(t) * 32 + gc16 * 8, \
            &lds[(t) & 3][0][((j) * 128 + wid * 16) * 32])
#define STAGE_B(t, j)                                                                              \
    gload16(W + (long)(n0 + (j) * 128 + wid * 16 + srow) * (long)ldb + koff + (long)(t) * 32 + gc16 * 8, \
            &lds[(t) & 3][1][((j) * 128 + wid * 16) * 32])

    // prologue: stage K-tiles 0,1,2 (12 loads/thread)
    STAGE_A(0, 0); STAGE_A(0, 1); STAGE_B(0, 0); STAGE_B(0, 1);
    STAGE_A(1, 0); STAGE_A(1, 1); STAGE_B(1, 0); STAGE_B(1, 1);
    STAGE_A(2, 0); STAGE_A(2, 1); STAGE_B(2, 0); STAGE_B(2, 1);
    asm volatile("s_waitcnt vmcnt(8)" ::: "memory");   // K-tile 0 resident
    __builtin_amdgcn_s_barrier();
    __builtin_amdgcn_sched_barrier(0);

    const int nt = K >> 5;
    for (int t = 0; t < nt; ++t) {
        const u16* Ab = &lds[t & 3][0][0];
        const u16* Bb = &lds[t & 3][1][0];
        bf16x8 afrg[4], bfrg[4];
        // ---- phase 1: A frags 0-3 + B frags 0-3 ----
#pragma unroll
        for (int f = 0; f < 4; ++f)
            afrg[f] = *(const bf16x8*)&Ab[(wr * 128 + f * 16 + l15) * 32 + ((lhi ^ sw) << 3)];
#pragma unroll
        for (int f = 0; f < 4; ++f)
            bfrg[f] = *(const bf16x8*)&Bb[(wc * 64 + f * 16 + l15) * 32 + ((lhi ^ sw) << 3)];
        if (t + 3 < nt) { STAGE_A(t + 3, 0); STAGE_A(t + 3, 1); }
        __builtin_amdgcn_s_barrier();
        __builtin_amdgcn_s_setprio(1);
#pragma unroll
        for (int i = 0; i < 4; ++i)
#pragma unroll
            for (int j = 0; j < 4; ++j)
                acc[i][j] = __builtin_amdgcn_mfma_f32_16x16x32_bf16(afrg[i], bfrg[j], acc[i][j], 0, 0, 0);
        __builtin_amdgcn_s_setprio(0);
        // ---- phase 2: A frags 4-7 (B reused in registers; no hazard -> no barrier) ----
#pragma unroll
        for (int f = 0; f < 4; ++f)
            afrg[f] = *(const bf16x8*)&Ab[(wr * 128 + (f + 4) * 16 + l15) * 32 + ((lhi ^ sw) << 3)];
        if (t + 3 < nt) { STAGE_B(t + 3, 0); STAGE_B(t + 3, 1); }
        __builtin_amdgcn_s_barrier();
        __builtin_amdgcn_s_setprio(1);
#pragma unroll
        for (int i = 0; i < 4; ++i)
#pragma unroll
            for (int j = 0; j < 4; ++j)
                acc[i + 4][j] = __builtin_amdgcn_mfma_f32_16x16x32_bf16(afrg[i], bfrg[j], acc[i + 4][j], 0, 0, 0);
        __builtin_amdgcn_s_setprio(0);
        // ---- end of iteration: ensure K-tile t+1 resident for all waves ----
        const int rem = nt - 2 - t;
        if (rem >= 2)      { asm volatile("s_waitcnt vmcnt(8)" ::: "memory"); }
        else if (rem == 1) { asm volatile("s_waitcnt vmcnt(4)" ::: "memory"); }
        else if (rem == 0) { asm volatile("s_waitcnt vmcnt(0)" ::: "memory"); }
        __builtin_amdgcn_s_barrier();
        __builtin_amdgcn_sched_barrier(0);
    }
#undef STAGE_A
#undef STAGE_B

#pragma unroll
    for (int i = 0; i < 8; ++i) {
#pragma unroll
        for (int j = 0; j < 4; ++j) {
#pragma unroll
            for (int r = 0; r < 4; ++r) {
                int row = m0 + wr * 128 + i * 16 + lhi * 4 + r;
                int col = n0 + wc * 64 + j * 16 + l15;
                long idx = (long)row * N + col;
                float v = acc[i][j][r];
                if (MODE == 2) v += addv[idx];
                if (MODE == 1) Cb[idx] = f2bf(v);
                else Cf[zoff + idx] = v;
            }
        }
    }
}

// ---------------- split-K reducers ----------------
__global__ __launch_bounds__(256) void reduce_add_kernel(const float* __restrict__ p0,
                                                         const float* __restrict__ p1,
                                                         const float* __restrict__ add,
                                                         float* __restrict__ out) {
    long i = ((long)blockIdx.x * 256 + threadIdx.x) * 4;
    f32x4 a = *(const f32x4*)(p0 + i);
    f32x4 b = *(const f32x4*)(p1 + i);
    f32x4 c = *(const f32x4*)(add + i);
    f32x4 o;
#pragma unroll
    for (int j = 0; j < 4; ++j) o[j] = a[j] + b[j] + c[j];
    *(f32x4*)(out + i) = o;
}

__global__ __launch_bounds__(256) void reduce4_bf16_kernel(const float* __restrict__ p,
                                                           u16* __restrict__ outb) {
    long i = ((long)blockIdx.x * 256 + threadIdx.x) * 4;   // over 4096*256
    const long S = 4096L * 256;
    f32x4 a = *(const f32x4*)(p + i);
    f32x4 b = *(const f32x4*)(p + S + i);
    f32x4 c = *(const f32x4*)(p + 2 * S + i);
    f32x4 d = *(const f32x4*)(p + 3 * S + i);
    union { uint2 v; u16 u[4]; } o;
#pragma unroll
    for (int j = 0; j < 4; ++j) o.u[j] = f2bf(a[j] + b[j] + c[j] + d[j]);
    *(uint2*)(outb + i) = o.v;
}

// ---------------- causal depthwise conv (K=4) + SiLU ----------------
__global__ __launch_bounds__(256) void conv_silu_kernel(const u16* __restrict__ xz,
                                                        const float* __restrict__ cw,
                                                        const float* __restrict__ cb,
                                                        float* __restrict__ xs_out,
                                                        u16* __restrict__ act_out) {
    const int d0 = (blockIdx.x * 256 + threadIdx.x) * 8;
    const int bl = blockIdx.y;
    const int l = bl & (L_SEQ - 1);
    float acc[8];
    float wt[8][4];
#pragma unroll
    for (int j = 0; j < 8; ++j) {
        f32x4 wj = *(const f32x4*)(cw + (d0 + j) * 4);
        wt[j][0] = wj[0]; wt[j][1] = wj[1]; wt[j][2] = wj[2]; wt[j][3] = wj[3];
        acc[j] = cb[d0 + j];
    }
#pragma unroll
    for (int k = 0; k < 4; ++k) {
        int ls = l + k - 3;
        if (ls >= 0) {
            union { uint4 v; u16 u[8]; } xv;
            xv.v = *(const uint4*)(xz + (long)(bl + k - 3) * (2 * DINNER) + d0);
#pragma unroll
            for (int j = 0; j < 8; ++j) acc[j] = fmaf(bf2f(xv.u[j]), wt[j][k], acc[j]);
        }
    }
    union { uint4 v; u16 u[8]; } ob;
    f32x4 o0, o1;
#pragma unroll
    for (int j = 0; j < 8; ++j) {
        float c = acc[j];
        float sv = c / (1.f + __expf(-c));
        if (j < 4) o0[j] = sv; else o1[j - 4] = sv;
        ob.u[j] = f2bf(sv);
    }
    long orow = (long)bl * DINNER + d0;
    *(f32x4*)(xs_out + orow) = o0;
    *(f32x4*)(xs_out + orow + 4) = o1;
    *(uint4*)(act_out + orow) = ob.v;
}

// ---------------- SSM chunked scan pass 1 ----------------
__global__ __launch_bounds__(256) void scan1_kernel(float* __restrict__ dpre,
                                                    const float* __restrict__ xs,
                                                    const u16* __restrict__ ssmb,
                                                    const float* __restrict__ Am,
                                                    const float* __restrict__ bdt,
                                                    float* __restrict__ hend,
                                                    float* __restrict__ sumd) {
    const int d = blockIdx.x * 256 + threadIdx.x;
    const int c = blockIdx.y;
    const int b = blockIdx.z;
    float a2[NSTATE];
#pragma unroll
    for (int n = 0; n < NSTATE; ++n) a2[n] = Am[d * NSTATE + n] * 1.4426950408889634f;
    float h[NSTATE];
#pragma unroll
    for (int n = 0; n < NSTATE; ++n) h[n] = 0.f;
    const float bd = bdt[d];
    float sd = 0.f;
    const long base = (long)b * L_SEQ + (long)c * CHUNK;
    for (int i = 0; i < CHUNK; ++i) {
        const long row = base + i;
        float dpv = dpre[row * DINNER + d] + bd;
        float delta = (dpv > 20.f) ? dpv : log1pf(__expf(dpv));
        dpre[row * DINNER + d] = delta;
        sd += delta;
        float dx = delta * xs[row * DINNER + d];
        const u16* sb = ssmb + row * 256;
#pragma unroll
        for (int n = 0; n < NSTATE; ++n)
            h[n] = __builtin_amdgcn_exp2f(delta * a2[n]) * h[n] + dx * bf2f(sb[128 + n]);
    }
    float* hb = hend + ((long)(b * NCHK + c) * DINNER + d) * NSTATE;
#pragma unroll
    for (int n = 0; n < NSTATE; n += 4)
        *(f32x4*)(hb + n) = (f32x4){h[n], h[n + 1], h[n + 2], h[n + 3]};
    sumd[(long)(b * NCHK + c) * DINNER + d] = sd;
}

// ---------------- pass 2: sequential combine across chunks (in place) ----------------
__global__ __launch_bounds__(256) void scan2_kernel(float* __restrict__ hend,
                                                    const float* __restrict__ sumd,
                                                    const float* __restrict__ Am) {
    const long idx = (long)blockIdx.x * 256 + threadIdx.x;
    const int n = (int)(idx & 15);
    const int d = (int)((idx >> 4) & (DINNER - 1));
    const int b = (int)(idx >> 16);
    const float a2 = Am[d * NSTATE + n] * 1.4426950408889634f;
    float carry = 0.f;
    for (int c = 0; c < NCHK; ++c) {
        const long soff = (long)(b * NCHK + c) * DINNER + d;
        const long hoff = soff * NSTATE + n;
        float he = hend[hoff];
        float P = __builtin_amdgcn_exp2f(a2 * sumd[soff]);
        hend[hoff] = carry;
        carry = he + P * carry;
    }
}

// ---------------- pass 3: re-scan with carry-in; fuses y, Dp*xs, gate-SiLU ----------------
__global__ __launch_bounds__(256) void scan3_kernel(const float* __restrict__ delta_,
                                                    const float* __restrict__ xs,
                                                    const u16* __restrict__ ssmb,
                                                    const u16* __restrict__ xz,
                                                    const float* __restrict__ Am,
                                                    const float* __restrict__ Dp,
                                                    const float* __restrict__ hinit,
                                                    u16* __restrict__ yb) {
    const int d = blockIdx.x * 256 + threadIdx.x;
    const int c = blockIdx.y;
    const int b = blockIdx.z;
    float a2[NSTATE];
#pragma unroll
    for (int n = 0; n < NSTATE; ++n) a2[n] = Am[d * NSTATE + n] * 1.4426950408889634f;
    float h[NSTATE];
    const float* hb = hinit + ((long)(b * NCHK + c) * DINNER + d) * NSTATE;
#pragma unroll
    for (int n = 0; n < NSTATE; n += 4) {
        f32x4 hv = *(const f32x4*)(hb + n);
        h[n] = hv[0]; h[n + 1] = hv[1]; h[n + 2] = hv[2]; h[n + 3] = hv[3];
    }
    const float dp = Dp[d];
    const long base = (long)b * L_SEQ + (long)c * CHUNK;
    for (int i = 0; i < CHUNK; ++i) {
        const long row = base + i;
        float delta = delta_[row * DINNER + d];
        float xt = xs[row * DINNER + d];
        float dx = delta * xt;
        const u16* sb = ssmb + row * 256;
        float y = 0.f;
#pragma unroll
        for (int n = 0; n < NSTATE; ++n) {
            float Bn = bf2f(sb[128 + n]);
            float Cn = bf2f(sb[144 + n]);
            h[n] = __builtin_amdgcn_exp2f(delta * a2[n]) * h[n] + dx * Bn;
            y = fmaf(h[n], Cn, y);
        }
        float g = bf2f(xz[row * (2 * DINNER) + DINNER + d]);
        float yv = (y + dp * xt) * (g / (1.f + __expf(-g)));
        yb[row * DINNER + d] = f2bf(yv);
    }
}

// ---------------- gated MLP activation: act = yy * silu(g) ----------------
__global__ __launch_bounds__(256) void gated_act_kernel(const u16* __restrict__ gy,
                                                        u16* __restrict__ actb) {
    long i = ((long)blockIdx.x * 256 + threadIdx.x) * 8;
    long m = i >> 13;
    long f = i & 8191;
    const u16* gp = gy + m * 16384 + f;
    union { uint4 v; u16 u[8]; } gu, yu, ob;
    gu.v = *(const uint4*)gp;
    yu.v = *(const uint4*)(gp + 8192);
#pragma unroll
    for (int j = 0; j < 8; ++j) {
        float g = bf2f(gu.u[j]);
        float yv = bf2f(yu.u[j]);
        ob.u[j] = f2bf(yv * (g / (1.f + __expf(-g))));
    }
    *(uint4*)(actb + i) = ob.v;
}

extern "C" void kernel_launch(void* const* d_in, const int* in_sizes, int n_in,
                              void* d_out, int out_size, void* d_ws, size_t ws_size,
                              hipStream_t stream) {
    const float* hidden = (const float*)d_in[0];
    const float* ln1w   = (const float*)d_in[1];
    const float* ln1b   = (const float*)d_in[2];
    const float* W_in   = (const float*)d_in[3];
    const float* conv_w = (const float*)d_in[4];
    const float* conv_b = (const float*)d_in[5];
    const float* W_x    = (const float*)d_in[6];
    const float* W_dt   = (const float*)d_in[7];
    const float* b_dt   = (const float*)d_in[8];
    const float* Amat   = (const float*)d_in[9];
    const float* Dp     = (const float*)d_in[10];
    const float* W_out  = (const float*)d_in[11];
    const float* ln2w   = (const float*)d_in[12];
    const float* ln2b   = (const float*)d_in[13];
    const float* W_fc1  = (const float*)d_in[14];
    const float* W_fc2  = (const float*)d_in[15];
    float* out = (float*)d_out;

    char* ws = (char*)d_ws;
    const size_t SZ67 = 67108864;  // 64 MiB
    u16*   ACT   = (u16*)(ws);
    u16*   WB    = (u16*)(ws + SZ67);
    u16*   XZ    = (u16*)(ws + 2 * SZ67);
    float* XS    = (float*)(ws + 3 * SZ67);
    float* DELTA = (float*)(ws + 4 * SZ67);
    u16*   SSMB  = (u16*)(ws + 5 * SZ67);
    float* HS    = (float*)(ws + 5 * SZ67 + 2097152);
    u16*   GY    = XZ;
    float* HEND  = (float*)WB;                            // 32MB (scan scratch, inside WB)
    float* SUMD  = (float*)(ws + SZ67 + 33554432);        // 2MB
    float* PART2 = (float*)(ws + SZ67 + 37748736);        // 16MB (GEMM2 split-K partials, inside WB)
    float* PART  = DELTA;                                 // 64MB (G4/G6 split-K partials; DELTA dead then)

    // 1) LN1 -> ACT (bf16)
    ln_kernel<<<MROWS, 256, 0, stream>>>(hidden, ln1w, ln1b, ACT);
    // 2) W_in -> WB
    cvt_kernel<<<(int)((8192L * 2048) / 2048), 256, 0, stream>>>(W_in, WB, 8192L * 2048);
    // 3) GEMM1: XZ = ACT @ W_in^T   (M=4096, N=8192, K=2048)
    gemm8<1><<<dim3(8192 / 256, MROWS / 256), 512, 0, stream>>>(ACT, WB, nullptr, XZ, nullptr,
                                                                MROWS, 8192, 2048, 2048, 2048);
    // 4) conv + silu -> XS (f32), ACT (bf16)
    conv_silu_kernel<<<dim3(2, MROWS), 256, 0, stream>>>(XZ, conv_w, conv_b, XS, ACT);
    // 5) W_x (160x4096) -> WB zero-padded to 256 rows
    cvt_kernel<<<(int)((256L * 4096) / 2048), 256, 0, stream>>>(W_x, WB, 160L * 4096);
    // 6) GEMM2 split-K4: PART2[z] = ACT @ W_x^T (z-th K quarter), then reduce -> SSMB bf16
    gemm_bt<0><<<dim3(2, 32, 4), 256, 0, stream>>>(ACT, WB, PART2, nullptr, nullptr,
                                                   MROWS, 256, 1024, 4096, 4096);
    reduce4_bf16_kernel<<<1024, 256, 0, stream>>>(PART2, SSMB);
    // 7) W_dt -> WB
    cvt_kernel<<<(int)((4096L * 128) / 2048), 256, 0, stream>>>(W_dt, WB, 4096L * 128);
    // 8) GEMM3: DELTA = SSMB[:, :128] @ W_dt^T (M=4096, N=4096, K=128, lda=256)
    gemm8<0><<<dim3(4096 / 256, MROWS / 256), 512, 0, stream>>>(SSMB, WB, DELTA, nullptr, nullptr,
                                                                MROWS, 4096, 128, 256, 128);
    // 9) chunked scan (WB reused as HEND/SUMD scratch)
    scan1_kernel<<<dim3(DINNER / 256, NCHK, 2), 256, 0, stream>>>(DELTA, XS, SSMB, Amat, b_dt,
                                                                  HEND, SUMD);
    scan2_kernel<<<(2 * DINNER * NSTATE) / 256, 256, 0, stream>>>(HEND, SUMD, Amat);
    scan3_kernel<<<dim3(DINNER / 256, NCHK, 2), 256, 0, stream>>>(DELTA, XS, SSMB, XZ, Amat, Dp,
                                                                  HEND, ACT);
    // 10) W_out -> WB
    cvt_kernel<<<(int)((2048L * 4096) / 2048), 256, 0, stream>>>(W_out, WB, 2048L * 4096);
    // 11) GEMM4 split-K2: PART[z] = ACT @ W_out^T; reduce: HS = P0+P1+hidden
    gemm8<0><<<dim3(2048 / 256, MROWS / 256, 2), 512, 0, stream>>>(ACT, WB, PART, nullptr, nullptr,
                                                                   MROWS, 2048, 2048, 4096, 4096);
    reduce_add_kernel<<<(int)((4096L * 2048) / 1024), 256, 0, stream>>>(PART, PART + 4096L * 2048,
                                                                        hidden, HS);
    // 12) LN2 -> ACT
    ln_kernel<<<MROWS, 256, 0, stream>>>(HS, ln2w, ln2b, ACT);
    // 13) W_fc1 -> WB
    cvt_kernel<<<(int)((16384L * 2048) / 2048), 256, 0, stream>>>(W_fc1, WB, 16384L * 2048);
    // 14) GEMM5: GY = ACT @ W_fc1^T (M=4096, N=16384, K=2048), bf16 out
    gemm8<1><<<dim3(16384 / 256, MROWS / 256), 512, 0, stream>>>(ACT, WB, nullptr, GY, nullptr,
                                                                 MROWS, 16384, 2048, 2048, 2048);
    // 15) gated activation -> ACT
    gated_act_kernel<<<(int)((4096L * 8192) / 2048), 256, 0, stream>>>(GY, ACT);
    // 16) W_fc2 -> WB
    cvt_kernel<<<(int)((2048L * 8192) / 2048), 256, 0, stream>>>(W_fc2, WB, 2048L * 8192);
    // 17) GEMM6 split-K2: PART[z] = ACT @ W_fc2^T; reduce: out = P0+P1+HS
    gemm8<0><<<dim3(2048 / 256, MROWS / 256, 2), 512, 0, stream>>>(ACT, WB, PART, nullptr, nullptr,
                                                                   MROWS, 2048, 4096, 8192, 8192);
    reduce_add_kernel<<<(int)((4096L * 2048) / 1024), 256, 0, stream>>>(PART, PART + 4096L * 2048,
                                                                        HS, out);
}

// Round 6
// 1056.656 us; speedup vs baseline: 3.9288x; 1.0313x over previous
//
#include <hip/hip_runtime.h>
#include <hip/hip_bf16.h>

typedef unsigned short u16;
typedef unsigned int u32;

#define L_SEQ 2048
#define DMODEL 2048
#define DINNER 4096
#define NSTATE 16
#define MROWS 4096   // B*L
#define CHUNK 32
#define NCHK  64     // L_SEQ / CHUNK

typedef __bf16 bf16x8 __attribute__((ext_vector_type(8)));
typedef float f32x4 __attribute__((ext_vector_type(4)));

__device__ __forceinline__ u16 f2bf(float f) {
    union { float f; u32 u; } v; v.f = f;
    u32 u = v.u;
    u32 r = (u + 0x7fffu + ((u >> 16) & 1u)) >> 16;
    return (u16)r;
}
__device__ __forceinline__ float bf2f(u16 h) {
    union { u32 u; float f; } v; v.u = ((u32)h) << 16;
    return v.f;
}

__device__ __forceinline__ void gload16(const void* g, void* l) {
    __builtin_amdgcn_global_load_lds((const __attribute__((address_space(1))) void*)g,
                                     (__attribute__((address_space(3))) void*)l, 16, 0, 0);
}

// ---------------- f32 -> bf16 conversion (zero-pads tail beyond nsrc) ----------------
__global__ __launch_bounds__(256) void cvt_kernel(const float* __restrict__ src,
                                                  u16* __restrict__ dst, long nsrc) {
    long i = ((long)blockIdx.x * 256 + threadIdx.x) * 8;
    union { uint4 v; u16 u[8]; } o;
    if (i < nsrc) {
        f32x4 a = *(const f32x4*)(src + i);
        f32x4 b = *(const f32x4*)(src + i + 4);
#pragma unroll
        for (int j = 0; j < 4; ++j) { o.u[j] = f2bf(a[j]); o.u[4 + j] = f2bf(b[j]); }
    } else {
#pragma unroll
        for (int j = 0; j < 8; ++j) o.u[j] = 0;
    }
    *(uint4*)(dst + i) = o.v;
}

// ---------------- LayerNorm (D=2048) -> bf16 ----------------
__global__ __launch_bounds__(256) void ln_kernel(const float* __restrict__ in,
                                                 const float* __restrict__ w,
                                                 const float* __restrict__ b,
                                                 u16* __restrict__ out) {
    const long row = blockIdx.x;
    const float* x = in + row * DMODEL;
    const int t = threadIdx.x;
    f32x4 v0 = *(const f32x4*)(x + t * 8);
    f32x4 v1 = *(const f32x4*)(x + t * 8 + 4);
    float s = 0.f, sq = 0.f;
#pragma unroll
    for (int j = 0; j < 4; ++j) {
        s += v0[j] + v1[j];
        sq += v0[j] * v0[j] + v1[j] * v1[j];
    }
#pragma unroll
    for (int off = 32; off > 0; off >>= 1) {
        s += __shfl_down(s, off);
        sq += __shfl_down(sq, off);
    }
    __shared__ float red[8];
    __shared__ float stats[2];
    const int wid = t >> 6, lane = t & 63;
    if (lane == 0) { red[wid] = s; red[4 + wid] = sq; }
    __syncthreads();
    if (t == 0) {
        float S = red[0] + red[1] + red[2] + red[3];
        float Q = red[4] + red[5] + red[6] + red[7];
        float mu = S / (float)DMODEL;
        stats[0] = mu;
        stats[1] = rsqrtf(Q / (float)DMODEL - mu * mu + 1e-5f);
    }
    __syncthreads();
    float mu = stats[0], rstd = stats[1];
    union { uint4 v; u16 u[8]; } o;
#pragma unroll
    for (int j = 0; j < 8; ++j) {
        float xv = (j < 4) ? v0[j] : v1[j - 4];
        o.u[j] = f2bf((xv - mu) * rstd * w[t * 8 + j] + b[t * 8 + j]);
    }
    *(uint4*)(out + row * DMODEL + t * 8) = o.v;
}

// ---------------- fused split-K reduce + residual + LayerNorm -> bf16 (and f32 hs) ----------------
__global__ __launch_bounds__(256) void reduce_ln_kernel(const float* __restrict__ p0,
                                                        const float* __restrict__ p1,
                                                        const float* __restrict__ add,
                                                        const float* __restrict__ w,
                                                        const float* __restrict__ b,
                                                        float* __restrict__ hs_out,
                                                        u16* __restrict__ ln_out) {
    const long row = blockIdx.x;
    const long base = row * DMODEL;
    const int t = threadIdx.x;
    f32x4 v0, v1;
    {
        f32x4 a0 = *(const f32x4*)(p0 + base + t * 8);
        f32x4 a1 = *(const f32x4*)(p0 + base + t * 8 + 4);
        f32x4 b0 = *(const f32x4*)(p1 + base + t * 8);
        f32x4 b1 = *(const f32x4*)(p1 + base + t * 8 + 4);
        f32x4 c0 = *(const f32x4*)(add + base + t * 8);
        f32x4 c1 = *(const f32x4*)(add + base + t * 8 + 4);
#pragma unroll
        for (int j = 0; j < 4; ++j) { v0[j] = a0[j] + b0[j] + c0[j]; v1[j] = a1[j] + b1[j] + c1[j]; }
    }
    *(f32x4*)(hs_out + base + t * 8) = v0;
    *(f32x4*)(hs_out + base + t * 8 + 4) = v1;
    float s = 0.f, sq = 0.f;
#pragma unroll
    for (int j = 0; j < 4; ++j) {
        s += v0[j] + v1[j];
        sq += v0[j] * v0[j] + v1[j] * v1[j];
    }
#pragma unroll
    for (int off = 32; off > 0; off >>= 1) {
        s += __shfl_down(s, off);
        sq += __shfl_down(sq, off);
    }
    __shared__ float red[8];
    __shared__ float stats[2];
    const int wid = t >> 6, lane = t & 63;
    if (lane == 0) { red[wid] = s; red[4 + wid] = sq; }
    __syncthreads();
    if (t == 0) {
        float S = red[0] + red[1] + red[2] + red[3];
        float Q = red[4] + red[5] + red[6] + red[7];
        float mu = S / (float)DMODEL;
        stats[0] = mu;
        stats[1] = rsqrtf(Q / (float)DMODEL - mu * mu + 1e-5f);
    }
    __syncthreads();
    float mu = stats[0], rstd = stats[1];
    union { uint4 v; u16 u[8]; } o;
#pragma unroll
    for (int j = 0; j < 8; ++j) {
        float xv = (j < 4) ? v0[j] : v1[j - 4];
        o.u[j] = f2bf((xv - mu) * rstd * w[t * 8 + j] + b[t * 8 + j]);
    }
    *(uint4*)(ln_out + base + t * 8) = o.v;
}

// ---------------- 128x128 2-phase GEMM (used for small-N GEMM2, split-K capable) ----------------
template <int MODE>
__global__ __launch_bounds__(256) void gemm_bt(const u16* __restrict__ A,
                                               const u16* __restrict__ W,
                                               float* __restrict__ Cf,
                                               u16* __restrict__ Cb,
                                               const float* __restrict__ addv,
                                               int M, int N, int K, int lda, int ldb) {
    __shared__ u16 As[128 * 64];
    __shared__ u16 Bs[128 * 64];
    const int tid = threadIdx.x;
    const int wid = tid >> 6;
    const int lane = tid & 63;
    const int m0 = blockIdx.y << 7;
    const int n0 = blockIdx.x << 7;
    const long koff = (long)blockIdx.z * K;
    const long zoff = (long)blockIdx.z * M * N;
    const int wr = (wid >> 1) << 6;
    const int wc = (wid & 1) << 6;
    const int l15 = lane & 15;
    const int lhi = lane >> 4;

    f32x4 acc[4][4];
#pragma unroll
    for (int i = 0; i < 4; ++i)
#pragma unroll
        for (int j = 0; j < 4; ++j) acc[i][j] = (f32x4){0.f, 0.f, 0.f, 0.f};

    const int srow = (wid << 3) + (lane >> 3);
    const int scol = (lane & 7) << 3;

    const u16* aBase = A + (long)(m0 + srow) * lda + scol + koff;
    const u16* bBase = W + (long)(n0 + srow) * (long)ldb + scol + koff;

    for (int k0 = 0; k0 < K; k0 += 64) {
#pragma unroll
        for (int i = 0; i < 4; ++i) {
            gload16(aBase + (long)(i * 32) * lda + k0, &As[((i << 5) + (wid << 3)) << 6]);
            gload16(bBase + (long)(i * 32) * ldb + k0, &Bs[((i << 5) + (wid << 3)) << 6]);
        }
        __syncthreads();
#pragma unroll
        for (int kk = 0; kk < 64; kk += 32) {
            bf16x8 af[4], bfr[4];
#pragma unroll
            for (int i = 0; i < 4; ++i)
                af[i] = *(const bf16x8*)&As[((wr + (i << 4) + l15) << 6) + kk + (lhi << 3)];
#pragma unroll
            for (int j = 0; j < 4; ++j)
                bfr[j] = *(const bf16x8*)&Bs[((wc + (j << 4) + l15) << 6) + kk + (lhi << 3)];
#pragma unroll
            for (int i = 0; i < 4; ++i)
#pragma unroll
                for (int j = 0; j < 4; ++j)
                    acc[i][j] = __builtin_amdgcn_mfma_f32_16x16x32_bf16(af[i], bfr[j], acc[i][j], 0, 0, 0);
        }
        __syncthreads();
    }

#pragma unroll
    for (int i = 0; i < 4; ++i) {
#pragma unroll
        for (int j = 0; j < 4; ++j) {
#pragma unroll
            for (int r = 0; r < 4; ++r) {
                int row = m0 + wr + (i << 4) + (lhi << 2) + r;
                int col = n0 + wc + (j << 4) + l15;
                long idx = (long)row * N + col;
                float v = acc[i][j][r];
                if (MODE == 2) v += addv[idx];
                if (MODE == 1) Cb[idx] = f2bf(v);
                else Cf[zoff + idx] = v;
            }
        }
    }
}

// ---------------- 256x256 8-wave pipelined GEMM, BK=32, ring-4 LDS, split-K capable ----------------
// Block order: m-fastest within bijective XCD chunks (concurrent blocks share B-cols -> L2-resident B).
template <int MODE>
__global__ __launch_bounds__(512, 2) void gemm8(const u16* __restrict__ A,
                                                const u16* __restrict__ W,
                                                float* __restrict__ Cf,
                                                u16* __restrict__ Cb,
                                                const float* __restrict__ addv,
                                                int M, int N, int K, int lda, int ldb) {
    __shared__ u16 lds[4][2][256 * 32];   // [buf][A=0/B=1][row*32 + col]
    const int tid = threadIdx.x;
    const int wid = tid >> 6;        // 0..7
    const int lane = tid & 63;
    const int wr = wid >> 2;         // 0..1 : M-half (128 rows)
    const int wc = wid & 3;          // 0..3 : N-quarter (64 cols)
    const int l15 = lane & 15;
    const int lhi = lane >> 4;       // 0..3
    const int sw = (l15 >> 1) & 3;   // read-side swizzle index
    const long koff = (long)blockIdx.z * K;
    const long zoff = (long)blockIdx.z * M * N;

    // T1: bijective XCD-aware block swizzle; m-fastest tile order
    const int nwg = gridDim.x * gridDim.y;
    const int flat = blockIdx.y * gridDim.x + blockIdx.x;
    const int q8 = nwg >> 3, r8 = nwg & 7;
    const int xcd = flat & 7, lid = flat >> 3;
    const int swz = (xcd < r8 ? xcd * (q8 + 1) : r8 * (q8 + 1) + (xcd - r8) * q8) + lid;
    const int m0 = (swz % gridDim.y) << 8;   // m-fastest: consecutive blocks share B columns
    const int n0 = (swz / gridDim.y) << 8;

    const int srow = lane >> 2;                          // row within 16-row slab
    const int gc16 = (lane & 3) ^ ((lane >> 3) & 3);     // pre-swizzled source column slot

    f32x4 acc[8][4];
#pragma unroll
    for (int i = 0; i < 8; ++i)
#pragma unroll
        for (int j = 0; j < 4; ++j) acc[i][j] = (f32x4){0.f, 0.f, 0.f, 0.f};

#define STAGE_A(t, j)                                                                              \
    gload16(A + (long)(m0 + (j) * 128 + wid * 16 + srow) * lda + koff + (long)(t) * 32 + gc16 * 8, \
            &lds[(t) & 3][0][((j) * 128 + wid * 16) * 32])
#define STAGE_B(t, j)                                                                              \
    gload16(W + (long)(n0 + (j) * 128 + wid * 16 + srow) * (long)ldb + koff + (long)(t) * 32 + gc16 * 8, \
            &lds[(t) & 3][1][((j) * 128 + wid * 16) * 32])

    // prologue: stage K-tiles 0,1,2 (12 loads/thread)
    STAGE_A(0, 0); STAGE_A(0, 1); STAGE_B(0, 0); STAGE_B(0, 1);
    STAGE_A(1, 0); STAGE_A(1, 1); STAGE_B(1, 0); STAGE_B(1, 1);
    STAGE_A(2, 0); STAGE_A(2, 1); STAGE_B(2, 0); STAGE_B(2, 1);
    asm volatile("s_waitcnt vmcnt(8)" ::: "memory");   // K-tile 0 resident
    __builtin_amdgcn_s_barrier();
    __builtin_amdgcn_sched_barrier(0);

    const int nt = K >> 5;
    for (int t = 0; t < nt; ++t) {
        const u16* Ab = &lds[t & 3][0][0];
        const u16* Bb = &lds[t & 3][1][0];
        bf16x8 afrg[4], bfrg[4];
        // ---- phase 1: A frags 0-3 + B frags 0-3 ----
#pragma unroll
        for (int f = 0; f < 4; ++f)
            afrg[f] = *(const bf16x8*)&Ab[(wr * 128 + f * 16 + l15) * 32 + ((lhi ^ sw) << 3)];
#pragma unroll
        for (int f = 0; f < 4; ++f)
            bfrg[f] = *(const bf16x8*)&Bb[(wc * 64 + f * 16 + l15) * 32 + ((lhi ^ sw) << 3)];
        if (t + 3 < nt) { STAGE_A(t + 3, 0); STAGE_A(t + 3, 1); }
        __builtin_amdgcn_s_barrier();
        __builtin_amdgcn_s_setprio(1);
#pragma unroll
        for (int i = 0; i < 4; ++i)
#pragma unroll
            for (int j = 0; j < 4; ++j)
                acc[i][j] = __builtin_amdgcn_mfma_f32_16x16x32_bf16(afrg[i], bfrg[j], acc[i][j], 0, 0, 0);
        __builtin_amdgcn_s_setprio(0);
        // ---- phase 2: A frags 4-7 (B reused in registers) ----
#pragma unroll
        for (int f = 0; f < 4; ++f)
            afrg[f] = *(const bf16x8*)&Ab[(wr * 128 + (f + 4) * 16 + l15) * 32 + ((lhi ^ sw) << 3)];
        if (t + 3 < nt) { STAGE_B(t + 3, 0); STAGE_B(t + 3, 1); }
        __builtin_amdgcn_s_barrier();
        __builtin_amdgcn_s_setprio(1);
#pragma unroll
        for (int i = 0; i < 4; ++i)
#pragma unroll
            for (int j = 0; j < 4; ++j)
                acc[i + 4][j] = __builtin_amdgcn_mfma_f32_16x16x32_bf16(afrg[i], bfrg[j], acc[i + 4][j], 0, 0, 0);
        __builtin_amdgcn_s_setprio(0);
        // ---- end of iteration: ensure K-tile t+1 resident for all waves ----
        const int rem = nt - 2 - t;
        if (rem >= 2)      { asm volatile("s_waitcnt vmcnt(8)" ::: "memory"); }
        else if (rem == 1) { asm volatile("s_waitcnt vmcnt(4)" ::: "memory"); }
        else if (rem == 0) { asm volatile("s_waitcnt vmcnt(0)" ::: "memory"); }
        __builtin_amdgcn_s_barrier();
        __builtin_amdgcn_sched_barrier(0);
    }
#undef STAGE_A
#undef STAGE_B

#pragma unroll
    for (int i = 0; i < 8; ++i) {
#pragma unroll
        for (int j = 0; j < 4; ++j) {
#pragma unroll
            for (int r = 0; r < 4; ++r) {
                int row = m0 + wr * 128 + i * 16 + lhi * 4 + r;
                int col = n0 + wc * 64 + j * 16 + l15;
                long idx = (long)row * N + col;
                float v = acc[i][j][r];
                if (MODE == 2) v += addv[idx];
                if (MODE == 1) Cb[idx] = f2bf(v);
                else Cf[zoff + idx] = v;
            }
        }
    }
}

// ---------------- split-K reducers ----------------
__global__ __launch_bounds__(256) void reduce_add_kernel(const float* __restrict__ p0,
                                                         const float* __restrict__ p1,
                                                         const float* __restrict__ add,
                                                         float* __restrict__ out) {
    long i = ((long)blockIdx.x * 256 + threadIdx.x) * 4;
    f32x4 a = *(const f32x4*)(p0 + i);
    f32x4 b = *(const f32x4*)(p1 + i);
    f32x4 c = *(const f32x4*)(add + i);
    f32x4 o;
#pragma unroll
    for (int j = 0; j < 4; ++j) o[j] = a[j] + b[j] + c[j];
    *(f32x4*)(out + i) = o;
}

__global__ __launch_bounds__(256) void reduce4_bf16_kernel(const float* __restrict__ p,
                                                           u16* __restrict__ outb) {
    long i = ((long)blockIdx.x * 256 + threadIdx.x) * 4;   // over 4096*256
    const long S = 4096L * 256;
    f32x4 a = *(const f32x4*)(p + i);
    f32x4 b = *(const f32x4*)(p + S + i);
    f32x4 c = *(const f32x4*)(p + 2 * S + i);
    f32x4 d = *(const f32x4*)(p + 3 * S + i);
    union { uint2 v; u16 u[4]; } o;
#pragma unroll
    for (int j = 0; j < 4; ++j) o.u[j] = f2bf(a[j] + b[j] + c[j] + d[j]);
    *(uint2*)(outb + i) = o.v;
}

// ---------------- causal depthwise conv (K=4) + SiLU -> bf16 ----------------
__global__ __launch_bounds__(256) void conv_silu_kernel(const u16* __restrict__ xz,
                                                        const float* __restrict__ cw,
                                                        const float* __restrict__ cb,
                                                        u16* __restrict__ act_out) {
    const int d0 = (blockIdx.x * 256 + threadIdx.x) * 8;
    const int bl = blockIdx.y;
    const int l = bl & (L_SEQ - 1);
    float acc[8];
    float wt[8][4];
#pragma unroll
    for (int j = 0; j < 8; ++j) {
        f32x4 wj = *(const f32x4*)(cw + (d0 + j) * 4);
        wt[j][0] = wj[0]; wt[j][1] = wj[1]; wt[j][2] = wj[2]; wt[j][3] = wj[3];
        acc[j] = cb[d0 + j];
    }
#pragma unroll
    for (int k = 0; k < 4; ++k) {
        int ls = l + k - 3;
        if (ls >= 0) {
            union { uint4 v; u16 u[8]; } xv;
            xv.v = *(const uint4*)(xz + (long)(bl + k - 3) * (2 * DINNER) + d0);
#pragma unroll
            for (int j = 0; j < 8; ++j) acc[j] = fmaf(bf2f(xv.u[j]), wt[j][k], acc[j]);
        }
    }
    union { uint4 v; u16 u[8]; } ob;
#pragma unroll
    for (int j = 0; j < 8; ++j) {
        float c = acc[j];
        ob.u[j] = f2bf(c / (1.f + __expf(-c)));
    }
    *(uint4*)(act_out + (long)bl * DINNER + d0) = ob.v;
}

// ---------------- SSM chunked scan pass 1 (xs read as bf16) ----------------
__global__ __launch_bounds__(256) void scan1_kernel(float* __restrict__ dpre,
                                                    const u16* __restrict__ xs,
                                                    const u16* __restrict__ ssmb,
                                                    const float* __restrict__ Am,
                                                    const float* __restrict__ bdt,
                                                    float* __restrict__ hend,
                                                    float* __restrict__ sumd) {
    const int d = blockIdx.x * 256 + threadIdx.x;
    const int c = blockIdx.y;
    const int b = blockIdx.z;
    float a2[NSTATE];
#pragma unroll
    for (int n = 0; n < NSTATE; ++n) a2[n] = Am[d * NSTATE + n] * 1.4426950408889634f;
    float h[NSTATE];
#pragma unroll
    for (int n = 0; n < NSTATE; ++n) h[n] = 0.f;
    const float bd = bdt[d];
    float sd = 0.f;
    const long base = (long)b * L_SEQ + (long)c * CHUNK;
    for (int i = 0; i < CHUNK; ++i) {
        const long row = base + i;
        float dpv = dpre[row * DINNER + d] + bd;
        float delta = (dpv > 20.f) ? dpv : log1pf(__expf(dpv));
        dpre[row * DINNER + d] = delta;
        sd += delta;
        float dx = delta * bf2f(xs[row * DINNER + d]);
        const u16* sb = ssmb + row * 256;
#pragma unroll
        for (int n = 0; n < NSTATE; ++n)
            h[n] = __builtin_amdgcn_exp2f(delta * a2[n]) * h[n] + dx * bf2f(sb[128 + n]);
    }
    float* hb = hend + ((long)(b * NCHK + c) * DINNER + d) * NSTATE;
#pragma unroll
    for (int n = 0; n < NSTATE; n += 4)
        *(f32x4*)(hb + n) = (f32x4){h[n], h[n + 1], h[n + 2], h[n + 3]};
    sumd[(long)(b * NCHK + c) * DINNER + d] = sd;
}

// ---------------- pass 2: sequential combine across chunks (in place) ----------------
__global__ __launch_bounds__(256) void scan2_kernel(float* __restrict__ hend,
                                                    const float* __restrict__ sumd,
                                                    const float* __restrict__ Am) {
    const long idx = (long)blockIdx.x * 256 + threadIdx.x;
    const int n = (int)(idx & 15);
    const int d = (int)((idx >> 4) & (DINNER - 1));
    const int b = (int)(idx >> 16);
    const float a2 = Am[d * NSTATE + n] * 1.4426950408889634f;
    float carry = 0.f;
    for (int c = 0; c < NCHK; ++c) {
        const long soff = (long)(b * NCHK + c) * DINNER + d;
        const long hoff = soff * NSTATE + n;
        float he = hend[hoff];
        float P = __builtin_amdgcn_exp2f(a2 * sumd[soff]);
        hend[hoff] = carry;
        carry = he + P * carry;
    }
}

// ---------------- pass 3: re-scan with carry-in; fuses y, Dp*xs, gate-SiLU ----------------
// xs and yb may alias (exact per-element in-place: each element read then written by same thread).
__global__ __launch_bounds__(256) void scan3_kernel(const float* __restrict__ delta_,
                                                    const u16* __restrict__ xs,
                                                    const u16* __restrict__ ssmb,
                                                    const u16* __restrict__ xz,
                                                    const float* __restrict__ Am,
                                                    const float* __restrict__ Dp,
                                                    const float* __restrict__ hinit,
                                                    u16* __restrict__ yb) {
    const int d = blockIdx.x * 256 + threadIdx.x;
    const int c = blockIdx.y;
    const int b = blockIdx.z;
    float a2[NSTATE];
#pragma unroll
    for (int n = 0; n < NSTATE; ++n) a2[n] = Am[d * NSTATE + n] * 1.4426950408889634f;
    float h[NSTATE];
    const float* hb = hinit + ((long)(b * NCHK + c) * DINNER + d) * NSTATE;
#pragma unroll
    for (int n = 0; n < NSTATE; n += 4) {
        f32x4 hv = *(const f32x4*)(hb + n);
        h[n] = hv[0]; h[n + 1] = hv[1]; h[n + 2] = hv[2]; h[n + 3] = hv[3];
    }
    const float dp = Dp[d];
    const long base = (long)b * L_SEQ + (long)c * CHUNK;
    for (int i = 0; i < CHUNK; ++i) {
        const long row = base + i;
        float delta = delta_[row * DINNER + d];
        float xt = bf2f(xs[row * DINNER + d]);
        float dx = delta * xt;
        const u16* sb = ssmb + row * 256;
        float y = 0.f;
#pragma unroll
        for (int n = 0; n < NSTATE; ++n) {
            float Bn = bf2f(sb[128 + n]);
            float Cn = bf2f(sb[144 + n]);
            h[n] = __builtin_amdgcn_exp2f(delta * a2[n]) * h[n] + dx * Bn;
            y = fmaf(h[n], Cn, y);
        }
        float g = bf2f(xz[row * (2 * DINNER) + DINNER + d]);
        float yv = (y + dp * xt) * (g / (1.f + __expf(-g)));
        yb[row * DINNER + d] = f2bf(yv);
    }
}

// ---------------- gated MLP activation: act = yy * silu(g) ----------------
__global__ __launch_bounds__(256) void gated_act_kernel(const u16* __restrict__ gy,
                                                        u16* __restrict__ actb) {
    long i = ((long)blockIdx.x * 256 + threadIdx.x) * 8;
    long m = i >> 13;
    long f = i & 8191;
    const u16* gp = gy + m * 16384 + f;
    union { uint4 v; u16 u[8]; } gu, yu, ob;
    gu.v = *(const uint4*)gp;
    yu.v = *(const uint4*)(gp + 8192);
#pragma unroll
    for (int j = 0; j < 8; ++j) {
        float g = bf2f(gu.u[j]);
        float yv = bf2f(yu.u[j]);
        ob.u[j] = f2bf(yv * (g / (1.f + __expf(-g))));
    }
    *(uint4*)(actb + i) = ob.v;
}

extern "C" void kernel_launch(void* const* d_in, const int* in_sizes, int n_in,
                              void* d_out, int out_size, void* d_ws, size_t ws_size,
                              hipStream_t stream) {
    const float* hidden = (const float*)d_in[0];
    const float* ln1w   = (const float*)d_in[1];
    const float* ln1b   = (const float*)d_in[2];
    const float* W_in   = (const float*)d_in[3];
    const float* conv_w = (const float*)d_in[4];
    const float* conv_b = (const float*)d_in[5];
    const float* W_x    = (const float*)d_in[6];
    const float* W_dt   = (const float*)d_in[7];
    const float* b_dt   = (const float*)d_in[8];
    const float* Amat   = (const float*)d_in[9];
    const float* Dp     = (const float*)d_in[10];
    const float* W_out  = (const float*)d_in[11];
    const float* ln2w   = (const float*)d_in[12];
    const float* ln2b   = (const float*)d_in[13];
    const float* W_fc1  = (const float*)d_in[14];
    const float* W_fc2  = (const float*)d_in[15];
    float* out = (float*)d_out;

    char* ws = (char*)d_ws;
    const size_t SZ67 = 67108864;  // 64 MiB
    u16*   ACT   = (u16*)(ws);
    u16*   WB    = (u16*)(ws + SZ67);
    u16*   XZ    = (u16*)(ws + 2 * SZ67);
    float* DELTA = (float*)(ws + 4 * SZ67);
    u16*   SSMB  = (u16*)(ws + 5 * SZ67);
    float* HS    = (float*)(ws + 5 * SZ67 + 2097152);
    u16*   GY    = XZ;                                    // spans XZ + next slot (4096x16384 bf16)
    float* HEND  = (float*)WB;                            // 32MB (scan scratch, inside WB)
    float* SUMD  = (float*)(ws + SZ67 + 33554432);        // 2MB
    float* PART2 = (float*)(ws + SZ67 + 37748736);        // 16MB (GEMM2 split-K partials, inside WB)
    float* PART  = DELTA;                                 // 64MB (G4/G6 split-K partials; DELTA dead then)

    // 1) LN1 -> ACT (bf16)
    ln_kernel<<<MROWS, 256, 0, stream>>>(hidden, ln1w, ln1b, ACT);
    // 2) W_in -> WB
    cvt_kernel<<<(int)((8192L * 2048) / 2048), 256, 0, stream>>>(W_in, WB, 8192L * 2048);
    // 3) GEMM1: XZ = ACT @ W_in^T   (M=4096, N=8192, K=2048)
    gemm8<1><<<dim3(8192 / 256, MROWS / 256), 512, 0, stream>>>(ACT, WB, nullptr, XZ, nullptr,
                                                                MROWS, 8192, 2048, 2048, 2048);
    // 4) conv + silu -> ACT (bf16)
    conv_silu_kernel<<<dim3(2, MROWS), 256, 0, stream>>>(XZ, conv_w, conv_b, ACT);
    // 5) W_x (160x4096) -> WB zero-padded to 256 rows
    cvt_kernel<<<(int)((256L * 4096) / 2048), 256, 0, stream>>>(W_x, WB, 160L * 4096);
    // 6) GEMM2 split-K4: PART2[z] = ACT @ W_x^T (z-th K quarter), then reduce -> SSMB bf16
    gemm_bt<0><<<dim3(2, 32, 4), 256, 0, stream>>>(ACT, WB, PART2, nullptr, nullptr,
                                                   MROWS, 256, 1024, 4096, 4096);
    reduce4_bf16_kernel<<<1024, 256, 0, stream>>>(PART2, SSMB);
    // 7) W_dt -> WB
    cvt_kernel<<<(int)((4096L * 128) / 2048), 256, 0, stream>>>(W_dt, WB, 4096L * 128);
    // 8) GEMM3: DELTA = SSMB[:, :128] @ W_dt^T (M=4096, N=4096, K=128, lda=256)
    gemm8<0><<<dim3(4096 / 256, MROWS / 256), 512, 0, stream>>>(SSMB, WB, DELTA, nullptr, nullptr,
                                                                MROWS, 4096, 128, 256, 128);
    // 9) chunked scan; scan3 writes y in place over ACT (xs)
    scan1_kernel<<<dim3(DINNER / 256, NCHK, 2), 256, 0, stream>>>(DELTA, ACT, SSMB, Amat, b_dt,
                                                                  HEND, SUMD);
    scan2_kernel<<<(2 * DINNER * NSTATE) / 256, 256, 0, stream>>>(HEND, SUMD, Amat);
    scan3_kernel<<<dim3(DINNER / 256, NCHK, 2), 256, 0, stream>>>(DELTA, ACT, SSMB, XZ, Amat, Dp,
                                                                  HEND, ACT);
    // 10) W_out -> WB
    cvt_kernel<<<(int)((2048L * 4096) / 2048), 256, 0, stream>>>(W_out, WB, 2048L * 4096);
    // 11) GEMM4 split-K2 -> PART; fused reduce+residual+LN2: HS, ACT
    gemm8<0><<<dim3(2048 / 256, MROWS / 256, 2), 512, 0, stream>>>(ACT, WB, PART, nullptr, nullptr,
                                                                   MROWS, 2048, 2048, 4096, 4096);
    reduce_ln_kernel<<<MROWS, 256, 0, stream>>>(PART, PART + 4096L * 2048, hidden,
                                                ln2w, ln2b, HS, ACT);
    // 13) W_fc1 -> WB
    cvt_kernel<<<(int)((16384L * 2048) / 2048), 256, 0, stream>>>(W_fc1, WB, 16384L * 2048);
    // 14) GEMM5: GY = ACT @ W_fc1^T (M=4096, N=16384, K=2048), bf16 out
    gemm8<1><<<dim3(16384 / 256, MROWS / 256), 512, 0, stream>>>(ACT, WB, nullptr, GY, nullptr,
                                                                 MROWS, 16384, 2048, 2048, 2048);
    // 15) gated activation -> ACT
    gated_act_kernel<<<(int)((4096L * 8192) / 2048), 256, 0, stream>>>(GY, ACT);
    // 16) W_fc2 -> WB
    cvt_kernel<<<(int)((2048L * 8192) / 2048), 256, 0, stream>>>(W_fc2, WB, 2048L * 8192);
    // 17) GEMM6 split-K2: PART[z] = ACT @ W_fc2^T; reduce: out = P0+P1+HS
    gemm8<0><<<dim3(2048 / 256, MROWS / 256, 2), 512, 0, stream>>>(ACT, WB, PART, nullptr, nullptr,
                                                                   MROWS, 2048, 4096, 8192, 8192);
    reduce_add_kernel<<<(int)((4096L * 2048) / 1024), 256, 0, stream>>>(PART, PART + 4096L * 2048,
                                                                        HS, out);
}

// Round 7
// 1001.075 us; speedup vs baseline: 4.1470x; 1.0555x over previous
//
#include <hip/hip_runtime.h>
#include <hip/hip_bf16.h>

typedef unsigned short u16;
typedef unsigned int u32;

#define L_SEQ 2048
#define DMODEL 2048
#define DINNER 4096
#define NSTATE 16
#define MROWS 4096   // B*L
#define CHUNK 32
#define NCHK  64     // L_SEQ / CHUNK

typedef __bf16 bf16x8 __attribute__((ext_vector_type(8)));
typedef float f32x4 __attribute__((ext_vector_type(4)));

__device__ __forceinline__ u16 f2bf(float f) {
    union { float f; u32 u; } v; v.f = f;
    u32 u = v.u;
    u32 r = (u + 0x7fffu + ((u >> 16) & 1u)) >> 16;
    return (u16)r;
}
__device__ __forceinline__ float bf2f(u16 h) {
    union { u32 u; float f; } v; v.u = ((u32)h) << 16;
    return v.f;
}

__device__ __forceinline__ void gload16(const void* g, void* l) {
    __builtin_amdgcn_global_load_lds((const __attribute__((address_space(1))) void*)g,
                                     (__attribute__((address_space(3))) void*)l, 16, 0, 0);
}

// ---------------- f32 -> bf16 conversion (zero-pads tail beyond nsrc) ----------------
__global__ __launch_bounds__(256) void cvt_kernel(const float* __restrict__ src,
                                                  u16* __restrict__ dst, long nsrc) {
    long i = ((long)blockIdx.x * 256 + threadIdx.x) * 8;
    union { uint4 v; u16 u[8]; } o;
    if (i < nsrc) {
        f32x4 a = *(const f32x4*)(src + i);
        f32x4 b = *(const f32x4*)(src + i + 4);
#pragma unroll
        for (int j = 0; j < 4; ++j) { o.u[j] = f2bf(a[j]); o.u[4 + j] = f2bf(b[j]); }
    } else {
#pragma unroll
        for (int j = 0; j < 8; ++j) o.u[j] = 0;
    }
    *(uint4*)(dst + i) = o.v;
}

// ---------------- W_fc1 f32 -> bf16 with 32-row g/y interleave ----------------
// dst row r: g16=r>>5, k=r&31; src row = k<16 ? 16*g16+k : 8192+16*g16+(k-16).
// Interleaved GEMM5 output cols (32-granular) pair g/y in adjacent j-fragments.
__global__ __launch_bounds__(256) void cvt_fc1_kernel(const float* __restrict__ src,
                                                      u16* __restrict__ dst) {
    long id = (long)blockIdx.x * 256 + threadIdx.x;   // 16384 * 256 threads
    int r = (int)(id >> 8);
    int c8 = (int)(id & 255) * 8;
    int g16 = r >> 5, k = r & 31;
    int sr = (k < 16) ? (g16 * 16 + k) : (8192 + g16 * 16 + (k - 16));
    const float* s = src + (long)sr * 2048 + c8;
    f32x4 a = *(const f32x4*)s;
    f32x4 b = *(const f32x4*)(s + 4);
    union { uint4 v; u16 u[8]; } o;
#pragma unroll
    for (int j = 0; j < 4; ++j) { o.u[j] = f2bf(a[j]); o.u[4 + j] = f2bf(b[j]); }
    *(uint4*)(dst + (long)r * 2048 + c8) = o.v;
}

// ---------------- LayerNorm (D=2048) -> bf16 ----------------
__global__ __launch_bounds__(256) void ln_kernel(const float* __restrict__ in,
                                                 const float* __restrict__ w,
                                                 const float* __restrict__ b,
                                                 u16* __restrict__ out) {
    const long row = blockIdx.x;
    const float* x = in + row * DMODEL;
    const int t = threadIdx.x;
    f32x4 v0 = *(const f32x4*)(x + t * 8);
    f32x4 v1 = *(const f32x4*)(x + t * 8 + 4);
    float s = 0.f, sq = 0.f;
#pragma unroll
    for (int j = 0; j < 4; ++j) {
        s += v0[j] + v1[j];
        sq += v0[j] * v0[j] + v1[j] * v1[j];
    }
#pragma unroll
    for (int off = 32; off > 0; off >>= 1) {
        s += __shfl_down(s, off);
        sq += __shfl_down(sq, off);
    }
    __shared__ float red[8];
    __shared__ float stats[2];
    const int wid = t >> 6, lane = t & 63;
    if (lane == 0) { red[wid] = s; red[4 + wid] = sq; }
    __syncthreads();
    if (t == 0) {
        float S = red[0] + red[1] + red[2] + red[3];
        float Q = red[4] + red[5] + red[6] + red[7];
        float mu = S / (float)DMODEL;
        stats[0] = mu;
        stats[1] = rsqrtf(Q / (float)DMODEL - mu * mu + 1e-5f);
    }
    __syncthreads();
    float mu = stats[0], rstd = stats[1];
    union { uint4 v; u16 u[8]; } o;
#pragma unroll
    for (int j = 0; j < 8; ++j) {
        float xv = (j < 4) ? v0[j] : v1[j - 4];
        o.u[j] = f2bf((xv - mu) * rstd * w[t * 8 + j] + b[t * 8 + j]);
    }
    *(uint4*)(out + row * DMODEL + t * 8) = o.v;
}

// ---------------- fused split-K reduce + residual + LayerNorm -> bf16 (and f32 hs) ----------------
__global__ __launch_bounds__(256) void reduce_ln_kernel(const float* __restrict__ p0,
                                                        const float* __restrict__ p1,
                                                        const float* __restrict__ add,
                                                        const float* __restrict__ w,
                                                        const float* __restrict__ b,
                                                        float* __restrict__ hs_out,
                                                        u16* __restrict__ ln_out) {
    const long row = blockIdx.x;
    const long base = row * DMODEL;
    const int t = threadIdx.x;
    f32x4 v0, v1;
    {
        f32x4 a0 = *(const f32x4*)(p0 + base + t * 8);
        f32x4 a1 = *(const f32x4*)(p0 + base + t * 8 + 4);
        f32x4 b0 = *(const f32x4*)(p1 + base + t * 8);
        f32x4 b1 = *(const f32x4*)(p1 + base + t * 8 + 4);
        f32x4 c0 = *(const f32x4*)(add + base + t * 8);
        f32x4 c1 = *(const f32x4*)(add + base + t * 8 + 4);
#pragma unroll
        for (int j = 0; j < 4; ++j) { v0[j] = a0[j] + b0[j] + c0[j]; v1[j] = a1[j] + b1[j] + c1[j]; }
    }
    *(f32x4*)(hs_out + base + t * 8) = v0;
    *(f32x4*)(hs_out + base + t * 8 + 4) = v1;
    float s = 0.f, sq = 0.f;
#pragma unroll
    for (int j = 0; j < 4; ++j) {
        s += v0[j] + v1[j];
        sq += v0[j] * v0[j] + v1[j] * v1[j];
    }
#pragma unroll
    for (int off = 32; off > 0; off >>= 1) {
        s += __shfl_down(s, off);
        sq += __shfl_down(sq, off);
    }
    __shared__ float red[8];
    __shared__ float stats[2];
    const int wid = t >> 6, lane = t & 63;
    if (lane == 0) { red[wid] = s; red[4 + wid] = sq; }
    __syncthreads();
    if (t == 0) {
        float S = red[0] + red[1] + red[2] + red[3];
        float Q = red[4] + red[5] + red[6] + red[7];
        float mu = S / (float)DMODEL;
        stats[0] = mu;
        stats[1] = rsqrtf(Q / (float)DMODEL - mu * mu + 1e-5f);
    }
    __syncthreads();
    float mu = stats[0], rstd = stats[1];
    union { uint4 v; u16 u[8]; } o;
#pragma unroll
    for (int j = 0; j < 8; ++j) {
        float xv = (j < 4) ? v0[j] : v1[j - 4];
        o.u[j] = f2bf((xv - mu) * rstd * w[t * 8 + j] + b[t * 8 + j]);
    }
    *(uint4*)(ln_out + base + t * 8) = o.v;
}

// ---------------- 128x128 2-phase GEMM (small-N GEMM2, split-K) ----------------
template <int MODE>
__global__ __launch_bounds__(256) void gemm_bt(const u16* __restrict__ A,
                                               const u16* __restrict__ W,
                                               float* __restrict__ Cf,
                                               u16* __restrict__ Cb,
                                               const float* __restrict__ addv,
                                               int M, int N, int K, int lda, int ldb) {
    __shared__ u16 As[128 * 64];
    __shared__ u16 Bs[128 * 64];
    const int tid = threadIdx.x;
    const int wid = tid >> 6;
    const int lane = tid & 63;
    const int m0 = blockIdx.y << 7;
    const int n0 = blockIdx.x << 7;
    const long koff = (long)blockIdx.z * K;
    const long zoff = (long)blockIdx.z * M * N;
    const int wr = (wid >> 1) << 6;
    const int wc = (wid & 1) << 6;
    const int l15 = lane & 15;
    const int lhi = lane >> 4;

    f32x4 acc[4][4];
#pragma unroll
    for (int i = 0; i < 4; ++i)
#pragma unroll
        for (int j = 0; j < 4; ++j) acc[i][j] = (f32x4){0.f, 0.f, 0.f, 0.f};

    const int srow = (wid << 3) + (lane >> 3);
    const int scol = (lane & 7) << 3;

    const u16* aBase = A + (long)(m0 + srow) * lda + scol + koff;
    const u16* bBase = W + (long)(n0 + srow) * (long)ldb + scol + koff;

    for (int k0 = 0; k0 < K; k0 += 64) {
#pragma unroll
        for (int i = 0; i < 4; ++i) {
            gload16(aBase + (long)(i * 32) * lda + k0, &As[((i << 5) + (wid << 3)) << 6]);
            gload16(bBase + (long)(i * 32) * ldb + k0, &Bs[((i << 5) + (wid << 3)) << 6]);
        }
        __syncthreads();
#pragma unroll
        for (int kk = 0; kk < 64; kk += 32) {
            bf16x8 af[4], bfr[4];
#pragma unroll
            for (int i = 0; i < 4; ++i)
                af[i] = *(const bf16x8*)&As[((wr + (i << 4) + l15) << 6) + kk + (lhi << 3)];
#pragma unroll
            for (int j = 0; j < 4; ++j)
                bfr[j] = *(const bf16x8*)&Bs[((wc + (j << 4) + l15) << 6) + kk + (lhi << 3)];
#pragma unroll
            for (int i = 0; i < 4; ++i)
#pragma unroll
                for (int j = 0; j < 4; ++j)
                    acc[i][j] = __builtin_amdgcn_mfma_f32_16x16x32_bf16(af[i], bfr[j], acc[i][j], 0, 0, 0);
        }
        __syncthreads();
    }

#pragma unroll
    for (int i = 0; i < 4; ++i) {
#pragma unroll
        for (int j = 0; j < 4; ++j) {
#pragma unroll
            for (int r = 0; r < 4; ++r) {
                int row = m0 + wr + (i << 4) + (lhi << 2) + r;
                int col = n0 + wc + (j << 4) + l15;
                long idx = (long)row * N + col;
                float v = acc[i][j][r];
                if (MODE == 1) Cb[idx] = f2bf(v);
                else Cf[zoff + idx] = v;
            }
        }
    }
}

// ---------------- 256x256 8-wave pipelined GEMM, K-64 iteration, 4 phases, ring-4 LDS ----------------
// 2 barriers + 2 counted vmcnt(4) per 64 MFMAs. Iter i reads K-32 tiles {2i,2i+1},
// stages {2i+2,2i+3}; buffer (2i+2)&3 was last read in iter i-1 phases P1/P2 (before that
// iter's end barrier) and (2i+3)&3 in P3/P4 (before same barrier) -> race-free.
// vmcnt(4) keeps 4 newest in flight; the 4 oldest (next-needed tile) are landed.
// MODE 0: f32 out (+split-K zoff); MODE 1: bf16 out; MODE 3: gated epilogue
// (interleaved g/y pairs in j/j+1) -> bf16 out of width N/2.
template <int MODE>
__global__ __launch_bounds__(512, 2) void gemm8(const u16* __restrict__ A,
                                                const u16* __restrict__ W,
                                                float* __restrict__ Cf,
                                                u16* __restrict__ Cb,
                                                int M, int N, int K, int lda, int ldb) {
    __shared__ u16 lds[4][2][256 * 32];   // [buf][A=0/B=1][row*32 + col]
    const int tid = threadIdx.x;
    const int wid = tid >> 6;        // 0..7
    const int lane = tid & 63;
    const int wr = wid >> 2;         // 0..1 : M-half (128 rows)
    const int wc = wid & 3;          // 0..3 : N-quarter (64 cols)
    const int l15 = lane & 15;
    const int lhi = lane >> 4;       // 0..3
    const int sw = (l15 >> 1) & 3;   // read-side swizzle index
    const long koff = (long)blockIdx.z * K;
    const long zoff = (long)blockIdx.z * M * N;

    // bijective XCD-aware block swizzle; m-fastest tile order (B L2-resident)
    const int nwg = gridDim.x * gridDim.y;
    const int flat = blockIdx.y * gridDim.x + blockIdx.x;
    const int q8 = nwg >> 3, r8 = nwg & 7;
    const int xcd = flat & 7, lid = flat >> 3;
    const int swz = (xcd < r8 ? xcd * (q8 + 1) : r8 * (q8 + 1) + (xcd - r8) * q8) + lid;
    const int m0 = (swz % gridDim.y) << 8;
    const int n0 = (swz / gridDim.y) << 8;

    const int srow = lane >> 2;                          // row within 16-row slab
    const int gc16 = (lane & 3) ^ ((lane >> 3) & 3);     // pre-swizzled source column slot

    f32x4 acc[8][4];
#pragma unroll
    for (int i = 0; i < 8; ++i)
#pragma unroll
        for (int j = 0; j < 4; ++j) acc[i][j] = (f32x4){0.f, 0.f, 0.f, 0.f};

#define STAGE_A(t, j)                                                                              \
    gload16(A + (long)(m0 + (j) * 128 + wid * 16 + srow) * lda + koff + (long)(t) * 32 + gc16 * 8, \
            &lds[(t) & 3][0][((j) * 128 + wid * 16) * 32])
#define STAGE_B(t, j)                                                                              \
    gload16(W + (long)(n0 + (j) * 128 + wid * 16 + srow) * (long)ldb + koff + (long)(t) * 32 + gc16 * 8, \
            &lds[(t) & 3][1][((j) * 128 + wid * 16) * 32])
#define RD_A(buf, f0)  *(const bf16x8*)&lds[buf][0][((wr * 128 + (f0) * 16 + l15)) * 32 + ((lhi ^ sw) << 3)]
#define RD_B(buf, f0)  *(const bf16x8*)&lds[buf][1][((wc * 64 + (f0) * 16 + l15)) * 32 + ((lhi ^ sw) << 3)]
#define MFMA16(ab)                                                                                  \
    __builtin_amdgcn_s_setprio(1);                                                                  \
    _Pragma("unroll")                                                                               \
    for (int ii = 0; ii < 4; ++ii)                                                                  \
        _Pragma("unroll")                                                                           \
        for (int jj = 0; jj < 4; ++jj)                                                              \
            acc[(ab) + ii][jj] = __builtin_amdgcn_mfma_f32_16x16x32_bf16(a[ii], bb[jj], acc[(ab) + ii][jj], 0, 0, 0); \
    __builtin_amdgcn_s_setprio(0);

    // prologue: stage K-32 tiles 0,1 (8 gloads)
    STAGE_A(0, 0); STAGE_A(0, 1); STAGE_B(0, 0); STAGE_B(0, 1);
    STAGE_A(1, 0); STAGE_A(1, 1); STAGE_B(1, 0); STAGE_B(1, 1);
    asm volatile("s_waitcnt vmcnt(4)" ::: "memory");   // tile 0 resident
    __builtin_amdgcn_s_barrier();
    __builtin_amdgcn_sched_barrier(0);

    const int nt2 = K >> 6;
    for (int i = 0; i < nt2; ++i) {
        const int t0 = 2 * i;
        const int b0 = t0 & 3, b1 = (t0 + 1) & 3;
        const bool more = (i + 1 < nt2);
        bf16x8 a[4], bb[4];
        // ---- P1: b0 frags A0-3 x B0-3 ----
#pragma unroll
        for (int f = 0; f < 4; ++f) a[f] = RD_A(b0, f);
#pragma unroll
        for (int f = 0; f < 4; ++f) bb[f] = RD_B(b0, f);
        if (more) { STAGE_A(t0 + 2, 0); STAGE_A(t0 + 2, 1); }
        MFMA16(0)
        // ---- P2: b0 frags A4-7 (B reused) ----
#pragma unroll
        for (int f = 0; f < 4; ++f) a[f] = RD_A(b0, f + 4);
        if (more) { STAGE_B(t0 + 2, 0); STAGE_B(t0 + 2, 1); }
        MFMA16(4)
        if (more) { asm volatile("s_waitcnt vmcnt(4)" ::: "memory"); }   // tile t0+1 resident
        else      { asm volatile("s_waitcnt vmcnt(0)" ::: "memory"); }
        __builtin_amdgcn_s_barrier();
        __builtin_amdgcn_sched_barrier(0);
        // ---- P3: b1 frags A0-3 x B0-3 ----
#pragma unroll
        for (int f = 0; f < 4; ++f) a[f] = RD_A(b1, f);
#pragma unroll
        for (int f = 0; f < 4; ++f) bb[f] = RD_B(b1, f);
        if (more) { STAGE_A(t0 + 3, 0); STAGE_A(t0 + 3, 1); }
        MFMA16(0)
        // ---- P4: b1 frags A4-7 ----
#pragma unroll
        for (int f = 0; f < 4; ++f) a[f] = RD_A(b1, f + 4);
        if (more) { STAGE_B(t0 + 3, 0); STAGE_B(t0 + 3, 1); }
        MFMA16(4)
        if (more) {
            asm volatile("s_waitcnt vmcnt(4)" ::: "memory");   // tile t0+2 resident
            __builtin_amdgcn_s_barrier();
            __builtin_amdgcn_sched_barrier(0);
        }
    }
#undef STAGE_A
#undef STAGE_B
#undef RD_A
#undef RD_B
#undef MFMA16

    if (MODE == 3) {
        // gated epilogue: cols interleaved 32-granular (16 g, 16 y); pair = (j even, j odd)
#pragma unroll
        for (int i = 0; i < 8; ++i) {
#pragma unroll
            for (int jp = 0; jp < 2; ++jp) {
                const int j = 2 * jp;
#pragma unroll
                for (int r = 0; r < 4; ++r) {
                    int row = m0 + wr * 128 + i * 16 + lhi * 4 + r;
                    int f = ((n0 + wc * 64) >> 1) + jp * 16 + l15;
                    float g = acc[i][j][r];
                    float yv = acc[i][j + 1][r];
                    Cb[(long)row * (N >> 1) + f] = f2bf(yv * (g / (1.f + __expf(-g))));
                }
            }
        }
    } else {
#pragma unroll
        for (int i = 0; i < 8; ++i) {
#pragma unroll
            for (int j = 0; j < 4; ++j) {
#pragma unroll
                for (int r = 0; r < 4; ++r) {
                    int row = m0 + wr * 128 + i * 16 + lhi * 4 + r;
                    int col = n0 + wc * 64 + j * 16 + l15;
                    long idx = (long)row * N + col;
                    if (MODE == 1) Cb[idx] = f2bf(acc[i][j][r]);
                    else Cf[zoff + idx] = acc[i][j][r];
                }
            }
        }
    }
}

// ---------------- split-K reducers ----------------
__global__ __launch_bounds__(256) void reduce_add_kernel(const float* __restrict__ p0,
                                                         const float* __restrict__ p1,
                                                         const float* __restrict__ add,
                                                         float* __restrict__ out) {
    long i = ((long)blockIdx.x * 256 + threadIdx.x) * 4;
    f32x4 a = *(const f32x4*)(p0 + i);
    f32x4 b = *(const f32x4*)(p1 + i);
    f32x4 c = *(const f32x4*)(add + i);
    f32x4 o;
#pragma unroll
    for (int j = 0; j < 4; ++j) o[j] = a[j] + b[j] + c[j];
    *(f32x4*)(out + i) = o;
}

__global__ __launch_bounds__(256) void reduce4_bf16_kernel(const float* __restrict__ p,
                                                           u16* __restrict__ outb) {
    long i = ((long)blockIdx.x * 256 + threadIdx.x) * 4;   // over 4096*256
    const long S = 4096L * 256;
    f32x4 a = *(const f32x4*)(p + i);
    f32x4 b = *(const f32x4*)(p + S + i);
    f32x4 c = *(const f32x4*)(p + 2 * S + i);
    f32x4 d = *(const f32x4*)(p + 3 * S + i);
    union { uint2 v; u16 u[4]; } o;
#pragma unroll
    for (int j = 0; j < 4; ++j) o.u[j] = f2bf(a[j] + b[j] + c[j] + d[j]);
    *(uint2*)(outb + i) = o.v;
}

// ---------------- causal depthwise conv (K=4) + SiLU -> bf16 ----------------
__global__ __launch_bounds__(256) void conv_silu_kernel(const u16* __restrict__ xz,
                                                        const float* __restrict__ cw,
                                                        const float* __restrict__ cb,
                                                        u16* __restrict__ act_out) {
    const int d0 = (blockIdx.x * 256 + threadIdx.x) * 8;
    const int bl = blockIdx.y;
    const int l = bl & (L_SEQ - 1);
    float acc[8];
    float wt[8][4];
#pragma unroll
    for (int j = 0; j < 8; ++j) {
        f32x4 wj = *(const f32x4*)(cw + (d0 + j) * 4);
        wt[j][0] = wj[0]; wt[j][1] = wj[1]; wt[j][2] = wj[2]; wt[j][3] = wj[3];
        acc[j] = cb[d0 + j];
    }
#pragma unroll
    for (int k = 0; k < 4; ++k) {
        int ls = l + k - 3;
        if (ls >= 0) {
            union { uint4 v; u16 u[8]; } xv;
            xv.v = *(const uint4*)(xz + (long)(bl + k - 3) * (2 * DINNER) + d0);
#pragma unroll
            for (int j = 0; j < 8; ++j) acc[j] = fmaf(bf2f(xv.u[j]), wt[j][k], acc[j]);
        }
    }
    union { uint4 v; u16 u[8]; } ob;
#pragma unroll
    for (int j = 0; j < 8; ++j) {
        float c = acc[j];
        ob.u[j] = f2bf(c / (1.f + __expf(-c)));
    }
    *(uint4*)(act_out + (long)bl * DINNER + d0) = ob.v;
}

// ---------------- SSM chunked scan pass 1 (xs read as bf16) ----------------
__global__ __launch_bounds__(256) void scan1_kernel(float* __restrict__ dpre,
                                                    const u16* __restrict__ xs,
                                                    const u16* __restrict__ ssmb,
                                                    const float* __restrict__ Am,
                                                    const float* __restrict__ bdt,
                                                    float* __restrict__ hend,
                                                    float* __restrict__ sumd) {
    const int d = blockIdx.x * 256 + threadIdx.x;
    const int c = blockIdx.y;
    const int b = blockIdx.z;
    float a2[NSTATE];
#pragma unroll
    for (int n = 0; n < NSTATE; ++n) a2[n] = Am[d * NSTATE + n] * 1.4426950408889634f;
    float h[NSTATE];
#pragma unroll
    for (int n = 0; n < NSTATE; ++n) h[n] = 0.f;
    const float bd = bdt[d];
    float sd = 0.f;
    const long base = (long)b * L_SEQ + (long)c * CHUNK;
    for (int i = 0; i < CHUNK; ++i) {
        const long row = base + i;
        float dpv = dpre[row * DINNER + d] + bd;
        float delta = (dpv > 20.f) ? dpv : log1pf(__expf(dpv));
        dpre[row * DINNER + d] = delta;
        sd += delta;
        float dx = delta * bf2f(xs[row * DINNER + d]);
        const u16* sb = ssmb + row * 256;
#pragma unroll
        for (int n = 0; n < NSTATE; ++n)
            h[n] = __builtin_amdgcn_exp2f(delta * a2[n]) * h[n] + dx * bf2f(sb[128 + n]);
    }
    float* hb = hend + ((long)(b * NCHK + c) * DINNER + d) * NSTATE;
#pragma unroll
    for (int n = 0; n < NSTATE; n += 4)
        *(f32x4*)(hb + n) = (f32x4){h[n], h[n + 1], h[n + 2], h[n + 3]};
    sumd[(long)(b * NCHK + c) * DINNER + d] = sd;
}

// ---------------- pass 2: sequential combine across chunks (in place) ----------------
__global__ __launch_bounds__(256) void scan2_kernel(float* __restrict__ hend,
                                                    const float* __restrict__ sumd,
                                                    const float* __restrict__ Am) {
    const long idx = (long)blockIdx.x * 256 + threadIdx.x;
    const int n = (int)(idx & 15);
    const int d = (int)((idx >> 4) & (DINNER - 1));
    const int b = (int)(idx >> 16);
    const float a2 = Am[d * NSTATE + n] * 1.4426950408889634f;
    float carry = 0.f;
    for (int c = 0; c < NCHK; ++c) {
        const long soff = (long)(b * NCHK + c) * DINNER + d;
        const long hoff = soff * NSTATE + n;
        float he = hend[hoff];
        float P = __builtin_amdgcn_exp2f(a2 * sumd[soff]);
        hend[hoff] = carry;
        carry = he + P * carry;
    }
}

// ---------------- pass 3: re-scan with carry-in; fuses y, Dp*xs, gate-SiLU ----------------
__global__ __launch_bounds__(256) void scan3_kernel(const float* __restrict__ delta_,
                                                    const u16* __restrict__ xs,
                                                    const u16* __restrict__ ssmb,
                                                    const u16* __restrict__ xz,
                                                    const float* __restrict__ Am,
                                                    const float* __restrict__ Dp,
                                                    const float* __restrict__ hinit,
                                                    u16* __restrict__ yb) {
    const int d = blockIdx.x * 256 + threadIdx.x;
    const int c = blockIdx.y;
    const int b = blockIdx.z;
    float a2[NSTATE];
#pragma unroll
    for (int n = 0; n < NSTATE; ++n) a2[n] = Am[d * NSTATE + n] * 1.4426950408889634f;
    float h[NSTATE];
    const float* hb = hinit + ((long)(b * NCHK + c) * DINNER + d) * NSTATE;
#pragma unroll
    for (int n = 0; n < NSTATE; n += 4) {
        f32x4 hv = *(const f32x4*)(hb + n);
        h[n] = hv[0]; h[n + 1] = hv[1]; h[n + 2] = hv[2]; h[n + 3] = hv[3];
    }
    const float dp = Dp[d];
    const long base = (long)b * L_SEQ + (long)c * CHUNK;
    for (int i = 0; i < CHUNK; ++i) {
        const long row = base + i;
        float delta = delta_[row * DINNER + d];
        float xt = bf2f(xs[row * DINNER + d]);
        float dx = delta * xt;
        const u16* sb = ssmb + row * 256;
        float y = 0.f;
#pragma unroll
        for (int n = 0; n < NSTATE; ++n) {
            float Bn = bf2f(sb[128 + n]);
            float Cn = bf2f(sb[144 + n]);
            h[n] = __builtin_amdgcn_exp2f(delta * a2[n]) * h[n] + dx * Bn;
            y = fmaf(h[n], Cn, y);
        }
        float g = bf2f(xz[row * (2 * DINNER) + DINNER + d]);
        float yv = (y + dp * xt) * (g / (1.f + __expf(-g)));
        yb[row * DINNER + d] = f2bf(yv);
    }
}

extern "C" void kernel_launch(void* const* d_in, const int* in_sizes, int n_in,
                              void* d_out, int out_size, void* d_ws, size_t ws_size,
                              hipStream_t stream) {
    const float* hidden = (const float*)d_in[0];
    const float* ln1w   = (const float*)d_in[1];
    const float* ln1b   = (const float*)d_in[2];
    const float* W_in   = (const float*)d_in[3];
    const float* conv_w = (const float*)d_in[4];
    const float* conv_b = (const float*)d_in[5];
    const float* W_x    = (const float*)d_in[6];
    const float* W_dt   = (const float*)d_in[7];
    const float* b_dt   = (const float*)d_in[8];
    const float* Amat   = (const float*)d_in[9];
    const float* Dp     = (const float*)d_in[10];
    const float* W_out  = (const float*)d_in[11];
    const float* ln2w   = (const float*)d_in[12];
    const float* ln2b   = (const float*)d_in[13];
    const float* W_fc1  = (const float*)d_in[14];
    const float* W_fc2  = (const float*)d_in[15];
    float* out = (float*)d_out;

    char* ws = (char*)d_ws;
    const size_t SZ67 = 67108864;  // 64 MiB
    u16*   ACT   = (u16*)(ws);
    u16*   WB    = (u16*)(ws + SZ67);
    u16*   XZ    = (u16*)(ws + 2 * SZ67);                 // xz (4096x8192 bf16) / later gated act
    float* DELTA = (float*)(ws + 4 * SZ67);
    u16*   SSMB  = (u16*)(ws + 5 * SZ67);
    float* HS    = (float*)(ws + 5 * SZ67 + 2097152);
    float* HEND  = (float*)WB;                            // 32MB (scan scratch, inside WB)
    float* SUMD  = (float*)(ws + SZ67 + 33554432);        // 2MB
    float* PART2 = (float*)(ws + SZ67 + 37748736);        // 16MB (GEMM2 split-K partials)
    float* PART  = DELTA;                                 // 64MB (G4/G6 split-K partials)

    // 1) LN1 -> ACT (bf16)
    ln_kernel<<<MROWS, 256, 0, stream>>>(hidden, ln1w, ln1b, ACT);
    // 2) W_in -> WB
    cvt_kernel<<<(int)((8192L * 2048) / 2048), 256, 0, stream>>>(W_in, WB, 8192L * 2048);
    // 3) GEMM1: XZ = ACT @ W_in^T   (M=4096, N=8192, K=2048)
    gemm8<1><<<dim3(8192 / 256, MROWS / 256), 512, 0, stream>>>(ACT, WB, nullptr, XZ,
                                                                MROWS, 8192, 2048, 2048, 2048);
    // 4) conv + silu -> ACT (bf16)
    conv_silu_kernel<<<dim3(2, MROWS), 256, 0, stream>>>(XZ, conv_w, conv_b, ACT);
    // 5) W_x (160x4096) -> WB zero-padded to 256 rows
    cvt_kernel<<<(int)((256L * 4096) / 2048), 256, 0, stream>>>(W_x, WB, 160L * 4096);
    // 6) GEMM2 split-K4 -> PART2; reduce -> SSMB bf16
    gemm_bt<0><<<dim3(2, 32, 4), 256, 0, stream>>>(ACT, WB, PART2, nullptr, nullptr,
                                                   MROWS, 256, 1024, 4096, 4096);
    reduce4_bf16_kernel<<<1024, 256, 0, stream>>>(PART2, SSMB);
    // 7) W_dt -> WB
    cvt_kernel<<<(int)((4096L * 128) / 2048), 256, 0, stream>>>(W_dt, WB, 4096L * 128);
    // 8) GEMM3: DELTA = SSMB[:, :128] @ W_dt^T (M=4096, N=4096, K=128, lda=256)
    gemm8<0><<<dim3(4096 / 256, MROWS / 256), 512, 0, stream>>>(SSMB, WB, DELTA, nullptr,
                                                                MROWS, 4096, 128, 256, 128);
    // 9) chunked scan; scan3 writes y in place over ACT (xs)
    scan1_kernel<<<dim3(DINNER / 256, NCHK, 2), 256, 0, stream>>>(DELTA, ACT, SSMB, Amat, b_dt,
                                                                  HEND, SUMD);
    scan2_kernel<<<(2 * DINNER * NSTATE) / 256, 256, 0, stream>>>(HEND, SUMD, Amat);
    scan3_kernel<<<dim3(DINNER / 256, NCHK, 2), 256, 0, stream>>>(DELTA, ACT, SSMB, XZ, Amat, Dp,
                                                                  HEND, ACT);
    // 10) W_out -> WB
    cvt_kernel<<<(int)((2048L * 4096) / 2048), 256, 0, stream>>>(W_out, WB, 2048L * 4096);
    // 11) GEMM4 split-K2 -> PART; fused reduce+residual+LN2: HS, ACT
    gemm8<0><<<dim3(2048 / 256, MROWS / 256, 2), 512, 0, stream>>>(ACT, WB, PART, nullptr,
                                                                   MROWS, 2048, 2048, 4096, 4096);
    reduce_ln_kernel<<<MROWS, 256, 0, stream>>>(PART, PART + 4096L * 2048, hidden,
                                                ln2w, ln2b, HS, ACT);
    // 13) W_fc1 -> WB (32-row g/y interleaved)
    cvt_fc1_kernel<<<16384, 256, 0, stream>>>(W_fc1, WB);
    // 14) GEMM5 fused-gated: XZ = (yy * silu(g)) with interleaved W_fc1 (N=16384 -> out 8192)
    gemm8<3><<<dim3(16384 / 256, MROWS / 256), 512, 0, stream>>>(ACT, WB, nullptr, XZ,
                                                                 MROWS, 16384, 2048, 2048, 2048);
    // 16) W_fc2 -> WB
    cvt_kernel<<<(int)((2048L * 8192) / 2048), 256, 0, stream>>>(W_fc2, WB, 2048L * 8192);
    // 17) GEMM6 split-K2: PART[z] = XZ @ W_fc2^T; reduce: out = P0+P1+HS
    gemm8<0><<<dim3(2048 / 256, MROWS / 256, 2), 512, 0, stream>>>(XZ, WB, PART, nullptr,
                                                                   MROWS, 2048, 4096, 8192, 8192);
    reduce_add_kernel<<<(int)((4096L * 2048) / 1024), 256, 0, stream>>>(PART, PART + 4096L * 2048,
                                                                        HS, out);
}